// Round 1
// baseline (352.951 us; speedup 1.0000x reference)
//
#include <hip/hip_runtime.h>
#include <hip/hip_bf16.h>
#include <math.h>
#include <stdint.h>

// ---------------------------------------------------------------------------
// Transformer block: x + attn(rms(x,g1)) -> x1 ; x1 + ffn(rms(x1,g2))
// B=2 T=2048 D=1024 H=16 Dh=64 FF=4096. All GEMMs bf16 MFMA 16x16x32.
// R9: QKV/FFN1/FFN2 moved from m97 2-barrier structure (~500 TF, MfmaUtil 20%)
//     to 256x256 8-phase counted-vmcnt template (T3+T4+T5 on top of T2):
//     raw s_barrier (no vmcnt(0) drain), s_waitcnt vmcnt(4) once per K-tile,
//     setprio(1) around each 16-MFMA cluster, 8 waves (2Mx4N) strided halves.
//     FFN2: split-K=4 (256 blocks, Ksub=1024) atomic into pre-inited d_out.
// Wo gemm + attention unchanged from R8 (next target if this lands).
// LDS tiles use XOR-swizzled 16B chunks (chunk j of row r lives at j^(r&7));
// rocprof shows SQ_LDS_BANK_CONFLICT == 0 for this scheme.
// ---------------------------------------------------------------------------

typedef __bf16 v8bf  __attribute__((ext_vector_type(8)));
typedef float  v4f   __attribute__((ext_vector_type(4)));

#define T_SEQ 2048
#define EXP2F(x) __builtin_amdgcn_exp2f(x)  // v_exp_f32 (2^x)

// swizzled fragment read: row R, k-elem offset ko (multiple of 8)
#define FRAG(base, R, ko) \
  (*(const v8bf*)((base) + (R) * 64 + (((((ko) >> 3) ^ ((R) & 7))) << 3)))

__device__ __forceinline__ void async_ld16(const void* g, void* l) {
  // global -> LDS direct, 16B/lane. LDS dest is wave-uniform base + lane*16.
  __builtin_amdgcn_global_load_lds(
      (const __attribute__((address_space(1))) uint32_t*)g,
      (__attribute__((address_space(3))) uint32_t*)l, 16, 0, 0);
}

// raw barrier: no implicit s_waitcnt vmcnt(0) (unlike __syncthreads).
// empty-asm memory clobbers pin compiler code motion of LDS ops across it.
__device__ __forceinline__ void wg_barrier() {
  asm volatile("" ::: "memory");
  __builtin_amdgcn_s_barrier();
  asm volatile("" ::: "memory");
}

// ---------------- 4x weight transpose (Wq,Wk,Wv,Wo) fused ------------------
__global__ __launch_bounds__(256) void transpose_w4(
    const float* __restrict__ Wq, const float* __restrict__ Wk,
    const float* __restrict__ Wv, const float* __restrict__ Wo,
    __hip_bfloat16* __restrict__ out)
{
  __shared__ float tile[32][33];
  const int z = blockIdx.z;
  const float* W = z == 0 ? Wq : z == 1 ? Wk : z == 2 ? Wv : Wo;
  const int n0 = blockIdx.x * 32, k0 = blockIdx.y * 32;
  const int tx = threadIdx.x, ty = threadIdx.y;  // 32 x 8
#pragma unroll
  for (int i = 0; i < 32; i += 8)
    tile[ty + i][tx] = W[(size_t)(k0 + ty + i) * 1024 + n0 + tx];
  __syncthreads();
  __hip_bfloat16* o = out + (size_t)z * 1024 * 1024;
#pragma unroll
  for (int i = 0; i < 32; i += 8)
    o[(size_t)(n0 + ty + i) * 1024 + k0 + tx] = __float2bfloat16(tile[tx][ty + i]);
}

// ---------------- generic weight transpose ----------------------------------
__global__ __launch_bounds__(256) void transpose_w(
    const float* __restrict__ W, __hip_bfloat16* __restrict__ WT,
    int K, int N, int ldo)
{
  __shared__ float tile[32][33];
  const int n0 = blockIdx.x * 32, k0 = blockIdx.y * 32;
  const int tx = threadIdx.x, ty = threadIdx.y;  // 32 x 8
#pragma unroll
  for (int i = 0; i < 32; i += 8)
    tile[ty + i][tx] = W[(size_t)(k0 + ty + i) * N + n0 + tx];
  __syncthreads();
#pragma unroll
  for (int i = 0; i < 32; i += 8)
    WT[(size_t)(n0 + ty + i) * ldo + k0 + tx] = __float2bfloat16(tile[tx][ty + i]);
}

// ---------------- V transpose: QKV V-part -> VTg[b][h][d][t] ---------------
__global__ __launch_bounds__(256) void transpose_v(
    const __hip_bfloat16* __restrict__ QKV, __hip_bfloat16* __restrict__ VTg)
{
  __shared__ float tile[32][33];
  const int t0 = blockIdx.x * 32;
  const int bh = blockIdx.y >> 1;
  const int dt = (blockIdx.y & 1) * 32;
  const int b = bh >> 4, h = bh & 15;
  const int tx = threadIdx.x, ty = threadIdx.y;  // 32 x 8
#pragma unroll
  for (int i = 0; i < 32; i += 8)
    tile[ty + i][tx] = __bfloat162float(
        QKV[(size_t)(b * T_SEQ + t0 + ty + i) * 3072 + 2048 + h * 64 + dt + tx]);
  __syncthreads();
#pragma unroll
  for (int i = 0; i < 32; i += 8)
    VTg[((size_t)bh * 64 + dt + ty + i) * T_SEQ + t0 + tx] =
        __float2bfloat16(tile[tx][ty + i]);
}

// ---------------- RMSNorm (fp32 in -> bf16 out, optional d_out init) -------
__global__ __launch_bounds__(256) void rmsnorm_kernel(
    const float* __restrict__ x, const float* __restrict__ g,
    __hip_bfloat16* __restrict__ out,
    const float* __restrict__ bias, float* __restrict__ dinit)
{
  const int row = blockIdx.x;
  const int t = threadIdx.x;
  const float4 v = ((const float4*)(x + (size_t)row * 1024))[t];
  float ss = v.x * v.x + v.y * v.y + v.z * v.z + v.w * v.w;
#pragma unroll
  for (int off = 32; off; off >>= 1) ss += __shfl_xor(ss, off, 64);
  __shared__ float red[4];
  if ((t & 63) == 0) red[t >> 6] = ss;
  __syncthreads();
  ss = red[0] + red[1] + red[2] + red[3];
  const float rs = rsqrtf(ss * (1.0f / 1024.0f) + 1e-6f);
  const float4 gv = ((const float4*)g)[t];
  __hip_bfloat16* o = out + (size_t)row * 1024 + t * 4;
  o[0] = __float2bfloat16(v.x * rs * gv.x);
  o[1] = __float2bfloat16(v.y * rs * gv.y);
  o[2] = __float2bfloat16(v.z * rs * gv.z);
  o[3] = __float2bfloat16(v.w * rs * gv.w);
  if (dinit) {
    const float4 bv = ((const float4*)bias)[t];
    float4 d;
    d.x = v.x + bv.x; d.y = v.y + bv.y; d.z = v.z + bv.z; d.w = v.w + bv.w;
    ((float4*)(dinit + (size_t)row * 1024))[t] = d;
  }
}

// ---------------- legacy GEMM (kept for Wo): C = A @ BT^T (+epilogue) ------
template <int MODE, int MT, int PX, int PY>
__global__ __launch_bounds__(256, 2) void gemm_bt(
    const __hip_bfloat16* __restrict__ A,
    const __hip_bfloat16* __restrict__ BT,
    const float* __restrict__ bias,
    const float* __restrict__ resid,
    __hip_bfloat16* __restrict__ outb,
    float* __restrict__ outf,
    int M, int N, int K, int Ksub)
{
  __shared__ __align__(16) __hip_bfloat16 As[32 * MT * 64];
  __shared__ __align__(16) __hip_bfloat16 Bs[128 * 64];
  const int tid = threadIdx.x;
  const int wave = tid >> 6, lane = tid & 63;
  const int quad = lane >> 4, l16 = lane & 15;

  int bx = blockIdx.x, by = blockIdx.y;
  {
    const int id = by * gridDim.x + bx;
    const int k = id & 7, s = id >> 3;
    const int pw = gridDim.x / PX, ph = gridDim.y / PY;
    bx = (k % PX) * pw + (s % pw);
    by = (k / PX) * ph + (s / pw);
  }
  const int m0 = by * (32 * MT), n0 = bx * 128;
  const size_t kb = (size_t)blockIdx.z * Ksub;
  const int wr = (wave >> 1) * (16 * MT), wc = (wave & 1) * 64;
  const int lrow = lane >> 3;
  const int scol = ((lane & 7) ^ lrow) * 8;

  v4f acc[MT][4];
#pragma unroll
  for (int i = 0; i < MT; i++)
#pragma unroll
    for (int j = 0; j < 4; j++)
#pragma unroll
      for (int c = 0; c < 4; c++) acc[i][j][c] = 0.0f;

  for (int k0 = 0; k0 < Ksub; k0 += 64) {
#pragma unroll
    for (int i = 0; i < MT + 4; i++) {
      const int c = wave * (MT + 4) + i;
      if (c < 4 * MT) {
        async_ld16(A + (size_t)(m0 + c * 8 + lrow) * K + kb + k0 + scol, As + c * 512);
      } else {
        const int cb = c - 4 * MT;
        async_ld16(BT + (size_t)(n0 + cb * 8 + lrow) * K + kb + k0 + scol,
                   Bs + cb * 512);
      }
    }
    __syncthreads();
#pragma unroll
    for (int ks = 0; ks < 64; ks += 32) {
      v8bf af[MT], bfr[4];
#pragma unroll
      for (int mt = 0; mt < MT; mt++)
        af[mt] = FRAG(As, wr + mt * 16 + l16, ks + quad * 8);
#pragma unroll
      for (int nt = 0; nt < 4; nt++)
        bfr[nt] = FRAG(Bs, wc + nt * 16 + l16, ks + quad * 8);
#pragma unroll
      for (int mt = 0; mt < MT; mt++)
#pragma unroll
        for (int nt = 0; nt < 4; nt++)
          acc[mt][nt] = __builtin_amdgcn_mfma_f32_16x16x32_bf16(
              af[mt], bfr[nt], acc[mt][nt], 0, 0, 0);
    }
    __syncthreads();
  }

#pragma unroll
  for (int mt = 0; mt < MT; mt++) {
#pragma unroll
    for (int r = 0; r < 4; r++) {
      const int gm = m0 + wr + mt * 16 + quad * 4 + r;
#pragma unroll
      for (int nt = 0; nt < 4; nt++) {
        const int gn = n0 + wc + nt * 16 + l16;
        float v = acc[mt][nt][r];
        if (MODE == 0) {
          outb[(size_t)gm * N + gn] = __float2bfloat16(v);
        } else if (MODE == 1) {
          outf[(size_t)gm * N + gn] = resid[(size_t)gm * N + gn] + v;
        } else if (MODE == 2) {
          v += bias[gn];
          const float u = 0.7978845608f * (v + 0.044715f * v * v * v);
          const float e = EXP2F(u * 2.885390082f);
          const float th = 1.0f - 2.0f * __builtin_amdgcn_rcpf(e + 1.0f);
          v = 0.5f * v * (1.0f + th);
          outb[(size_t)gm * N + gn] = __float2bfloat16(v);
        } else {
          atomicAdd(&outf[(size_t)gm * N + gn], v);
        }
      }
    }
  }
}

// ---------------- GEMM 256x256 8-phase (counted-vmcnt schedule) ------------
// C = A @ BT^T. A [M][K] bf16, BT [N][K] bf16. BM=BN=256, BK=64, 512 thr.
// 8 waves (2M x 4N); per-wave 128x64 output as STRIDED halves:
//   rows: mh*128 + wm*64 + (0..63)   cols: nh*128 + wn*32 + (0..31)
// so phase quadrant (mh,nh) touches exactly tile-halves A[mh], B[nh].
// Per K-tile, 4 phases, quadrant order (0,0),(0,1),(1,1),(1,0); each phase:
//   { ds_read new half-frags | issue 1 half-tile stage | bar |
//     setprio(1) 16xMFMA setprio(0) | [P3: vmcnt] | bar }
// Stage ledger (steady state), half-stages of tile t+1/t+2 (2 loads each):
//   P0(t): A1(t+1)  [buf^1 region A1 free: last read P2/P3(t-1), barriered]
//   P1(t): B0(t+1)  [free after P0(t-1) reads]
//   P2(t): A0(t+2)  [same-buf region A0 free: last read P1(t), barriered]
//   P3(t): B1(t+2)  [same-buf region B1 free: last read P2(t), barriered]
//   wait@P3(t): outstanding = {A0,B1(t+1), A1,B0(t+1), A0,B1(t+2)} = 12 loads
//   -> s_waitcnt vmcnt(4) drains 8 oldest = ALL of tile t+1, leaves t+2's 2.
// Tail: t+2>=NT issues skipped; wait degrades vmcnt(4)->vmcnt(0)->none.
// MODE 0: outb=bf16(C)  MODE 2: outb=bf16(gelu(C+bias))  MODE 4: atomicAdd(outf,C)
template <int MODE, int PX, int PY>
__global__ __launch_bounds__(512, 2) void gemm256(
    const __hip_bfloat16* __restrict__ A,
    const __hip_bfloat16* __restrict__ BT,
    const float* __restrict__ bias,
    __hip_bfloat16* __restrict__ outb,
    float* __restrict__ outf,
    int M, int N, int K, int Ksub)
{
  __shared__ __align__(16) __hip_bfloat16 As[2 * 256 * 64];  // 64 KiB
  __shared__ __align__(16) __hip_bfloat16 Bs[2 * 256 * 64];  // 64 KiB
  (void)M;
  const int tid = threadIdx.x;
  const int wave = tid >> 6, lane = tid & 63;
  const int quad = lane >> 4, l16 = lane & 15;
  const int wm = wave >> 2, wn = wave & 3;
  const int lrow = lane >> 3, scol = ((lane & 7) ^ lrow) * 8;

  int bx = blockIdx.x, by = blockIdx.y;
  {
    const int id = by * gridDim.x + bx;
    const int k = id & 7, s = id >> 3;
    const int pw = gridDim.x / PX, ph = gridDim.y / PY;
    bx = (k % PX) * pw + (s % pw);
    by = (k / PX) * ph + (s / pw);
  }
  const int m0 = by * 256, n0 = bx * 256;
  const size_t kb = (size_t)blockIdx.z * Ksub;
  const int NT = Ksub >> 6;
  const int cg = wave * 2;  // this wave's 2 row-group slots (of 16 per half)

  auto stageA = [&](int h, int tt) {
#pragma unroll
    for (int j = 0; j < 2; j++) {
      const int rg = cg + j;
      async_ld16(A + (size_t)(m0 + h * 128 + rg * 8 + lrow) * K + kb + tt * 64 + scol,
                 As + ((tt & 1) * 16384 + (h * 128 + rg * 8) * 64));
    }
  };
  auto stageB = [&](int h, int tt) {
#pragma unroll
    for (int j = 0; j < 2; j++) {
      const int rg = cg + j;
      async_ld16(BT + (size_t)(n0 + h * 128 + rg * 8 + lrow) * K + kb + tt * 64 + scol,
                 Bs + ((tt & 1) * 16384 + (h * 128 + rg * 8) * 64));
    }
  };

  v4f acc[8][4];
#pragma unroll
  for (int i = 0; i < 8; i++)
#pragma unroll
    for (int j = 0; j < 4; j++)
#pragma unroll
      for (int c = 0; c < 4; c++) acc[i][j][c] = 0.0f;

  // prologue: tile0 {A0,B0,B1,A1} + tile1 {A0,B1}; drain tile0 (8 of 12)
  stageA(0, 0); stageB(0, 0); stageB(1, 0); stageA(1, 0);
  if (NT > 1) {
    stageA(0, 1); stageB(1, 1);
    asm volatile("s_waitcnt vmcnt(4)" ::: "memory");
  } else {
    asm volatile("s_waitcnt vmcnt(0)" ::: "memory");
  }
  wg_barrier();

#define READ_A(mh)                                                          \
  _Pragma("unroll") for (int mt = 0; mt < 4; mt++)                          \
      _Pragma("unroll") for (int ks = 0; ks < 2; ks++)                      \
          af[mt][ks] =                                                      \
              FRAG(Ab, (mh) * 128 + wm * 64 + mt * 16 + l16, ks * 32 + quad * 8)
#define READ_B(dst, nh)                                                     \
  _Pragma("unroll") for (int nt = 0; nt < 2; nt++)                          \
      _Pragma("unroll") for (int ks = 0; ks < 2; ks++)                      \
          dst[nt][ks] =                                                     \
              FRAG(Bb, (nh) * 128 + wn * 32 + nt * 16 + l16, ks * 32 + quad * 8)
#define MM16(mh, bsrc, nh)                                                  \
  __builtin_amdgcn_s_setprio(1);                                            \
  _Pragma("unroll") for (int mt = 0; mt < 4; mt++)                          \
      _Pragma("unroll") for (int nt = 0; nt < 2; nt++)                      \
          _Pragma("unroll") for (int ks = 0; ks < 2; ks++)                  \
              acc[(mh) * 4 + mt][(nh) * 2 + nt] =                           \
                  __builtin_amdgcn_mfma_f32_16x16x32_bf16(                  \
                      af[mt][ks], bsrc[nt][ks],                             \
                      acc[(mh) * 4 + mt][(nh) * 2 + nt], 0, 0, 0);          \
  __builtin_amdgcn_s_setprio(0)

  for (int t = 0; t < NT; ++t) {
    const __hip_bfloat16* Ab = As + (t & 1) * 16384;
    const __hip_bfloat16* Bb = Bs + (t & 1) * 16384;
    v8bf af[4][2], b0[2][2], b1[2][2];
    // ---- P0: quadrant (0,0)
    READ_A(0); READ_B(b0, 0);
    if (t + 1 < NT) stageA(1, t + 1);
    wg_barrier();
    MM16(0, b0, 0);
    wg_barrier();
    // ---- P1: quadrant (0,1)
    READ_B(b1, 1);
    if (t + 1 < NT) stageB(0, t + 1);
    wg_barrier();
    MM16(0, b1, 1);
    wg_barrier();
    // ---- P2: quadrant (1,1)
    READ_A(1);
    if (t + 2 < NT) stageA(0, t + 2);
    wg_barrier();
    MM16(1, b1, 1);
    wg_barrier();
    // ---- P3: quadrant (1,0)
    if (t + 2 < NT) stageB(1, t + 2);
    wg_barrier();
    MM16(1, b0, 0);
    if (t + 2 < NT) {
      asm volatile("s_waitcnt vmcnt(4)" ::: "memory");  // drain tile t+1
    } else if (t + 1 < NT) {
      asm volatile("s_waitcnt vmcnt(0)" ::: "memory");  // tail drain
    }
    wg_barrier();
  }
#undef READ_A
#undef READ_B
#undef MM16

  // epilogue: C/D layout col=lane&15, row=quad*4+reg
#pragma unroll
  for (int ni = 0; ni < 4; ni++) {
    const int gn = n0 + (ni >> 1) * 128 + wn * 32 + (ni & 1) * 16 + l16;
    float bcol = 0.0f;
    if (MODE == 2) bcol = bias[gn];
#pragma unroll
    for (int mi = 0; mi < 8; mi++) {
      const int gmb = m0 + (mi >> 2) * 128 + wm * 64 + (mi & 3) * 16 + quad * 4;
#pragma unroll
      for (int r = 0; r < 4; r++) {
        float v = acc[mi][ni][r];
        const size_t idx = (size_t)(gmb + r) * N + gn;
        if (MODE == 0) {
          outb[idx] = __float2bfloat16(v);
        } else if (MODE == 2) {
          v += bcol;
          // tanh-GELU (max |err| ~1e-3 in h -> <1e-3 in final output)
          const float u = 0.7978845608f * (v + 0.044715f * v * v * v);
          const float e = EXP2F(u * 2.885390082f);  // exp(2u)
          const float th = 1.0f - 2.0f * __builtin_amdgcn_rcpf(e + 1.0f);
          v = 0.5f * v * (1.0f + th);
          outb[idx] = __float2bfloat16(v);
        } else {
          atomicAdd(&outf[idx], v);
        }
      }
    }
  }
}

// ---------------- flash attention (causal, no-max exp2 softmax) ------------
__global__ __launch_bounds__(256, 2) void attn_kernel(
    const __hip_bfloat16* __restrict__ QKV,
    const __hip_bfloat16* __restrict__ VTg,
    __hip_bfloat16* __restrict__ Y)
{
  __shared__ __align__(16) __hip_bfloat16 Ks[2 * 64 * 64];
  __shared__ __align__(16) __hip_bfloat16 Vs[2 * 64 * 64];
  __shared__ __align__(16) __hip_bfloat16 PsA[64 * 64];
  __shared__ __align__(16) __hip_bfloat16 PsB[64 * 64];

  const int tid = threadIdx.x;
  const int wave = tid >> 6, lane = tid & 63;
  const int quad = lane >> 4, l16 = lane & 15;
  const int blk = blockIdx.x;
  const int p = blk & 15, h = (blk >> 4) & 15, b = blk >> 8;
  const int qa = p, qb = 31 - p, kmax = qb;
  const size_t rowbase = (size_t)b * T_SEQ;
  const size_t vbase = (size_t)(b * 16 + h) * 64;
  const int lrow = lane >> 3, scol = ((lane & 7) ^ (lane >> 3)) * 8;

  const float QSC = 0.125f * 1.44269504f;
  v8bf aqA[2], aqB[2];
#pragma unroll
  for (int ks = 0; ks < 2; ks++) {
    v8bf q = *(const v8bf*)(QKV + (rowbase + qa * 64 + wave * 16 + l16) * 3072 +
                            h * 64 + ks * 32 + quad * 8);
#pragma unroll
    for (int j = 0; j < 8; j++) aqA[ks][j] = (__bf16)((float)q[j] * QSC);
    q = *(const v8bf*)(QKV + (rowbase + qb * 64 + wave * 16 + l16) * 3072 +
                       h * 64 + ks * 32 + quad * 8);
#pragma unroll
    for (int j = 0; j < 8; j++) aqB[ks][j] = (__bf16)((float)q[j] * QSC);
  }

  v4f oA[4], oB[4];
  float lpA[4], lpB[4];
#pragma unroll
  for (int i = 0; i < 4; i++) {
    lpA[i] = 0.0f; lpB[i] = 0.0f;
#pragma unroll
    for (int c = 0; c < 4; c++) { oA[i][c] = 0.0f; oB[i][c] = 0.0f; }
  }

  auto stage = [&](int kt, int buf) {
#pragma unroll
    for (int i = 0; i < 2; i++) {
      const int r8 = i * 32 + wave * 8;
      const int rr = r8 + lrow;
      async_ld16(QKV + (rowbase + kt * 64 + rr) * 3072 + 1024 + h * 64 + scol,
                 Ks + buf * 4096 + r8 * 64);
      async_ld16(VTg + (vbase + rr) * T_SEQ + kt * 64 + scol,
                 Vs + buf * 4096 + r8 * 64);
    }
  };
  stage(0, 0);

  auto softmax_store = [&](v4f s[4], float lp[4], __hip_bfloat16* Ps, bool diag) {
    if (diag) {
#pragma unroll
      for (int nt = 0; nt < 4; nt++) {
        const int colr = nt * 16 + l16;
#pragma unroll
        for (int r = 0; r < 4; r++)
          if (colr > wave * 16 + quad * 4 + r) s[nt][r] = -30000.0f;
      }
    }
#pragma unroll
    for (int r = 0; r < 4; r++) {
      const int row = wave * 16 + quad * 4 + r;
      const int rsw = (quad * 4 + r) & 7;
#pragma unroll
      for (int nt = 0; nt < 4; nt++) {
        const float e = EXP2F(s[nt][r]);
        lp[r] += e;
        const int chunk = (nt * 2 + (l16 >> 3)) ^ rsw;
        Ps[row * 64 + (chunk << 3) + (l16 & 7)] = __float2bfloat16(e);
      }
    }
  };

  for (int kt = 0; kt <= kmax; kt++) {
    __syncthreads();
    if (kt < kmax) stage(kt + 1, (kt + 1) & 1);
    const __hip_bfloat16* Kb = Ks + (kt & 1) * 4096;
    const __hip_bfloat16* Vb = Vs + (kt & 1) * 4096;
    const bool doA = (kt <= qa);

    {
      v8bf kf[2][4];
#pragma unroll
      for (int ks = 0; ks < 2; ks++)
#pragma unroll
        for (int nt = 0; nt < 4; nt++)
          kf[ks][nt] = FRAG(Kb, nt * 16 + l16, ks * 32 + quad * 8);

      v4f sB[4];
#pragma unroll
      for (int nt = 0; nt < 4; nt++)
#pragma unroll
        for (int c = 0; c < 4; c++) sB[nt][c] = 0.0f;
#pragma unroll
      for (int ks = 0; ks < 2; ks++)
#pragma unroll
        for (int nt = 0; nt < 4; nt++)
          sB[nt] = __builtin_amdgcn_mfma_f32_16x16x32_bf16(aqB[ks], kf[ks][nt],
                                                           sB[nt], 0, 0, 0);
      softmax_store(sB, lpB, PsB, kt == qb);

      if (doA) {
        v4f sA[4];
#pragma unroll
        for (int nt = 0; nt < 4; nt++)
#pragma unroll
          for (int c = 0; c < 4; c++) sA[nt][c] = 0.0f;
#pragma unroll
        for (int ks = 0; ks < 2; ks++)
#pragma unroll
          for (int nt = 0; nt < 4; nt++)
            sA[nt] = __builtin_amdgcn_mfma_f32_16x16x32_bf16(aqA[ks], kf[ks][nt],
                                                             sA[nt], 0, 0, 0);
        softmax_store(sA, lpA, PsA, kt == qa);
      }
    }

    {
      v8bf vf[2][4];
#pragma unroll
      for (int ks = 0; ks < 2; ks++)
#pragma unroll
        for (int nt = 0; nt < 4; nt++)
          vf[ks][nt] = FRAG(Vb, nt * 16 + l16, ks * 32 + quad * 8);
#pragma unroll
      for (int ks = 0; ks < 2; ks++) {
        const v8bf apB = FRAG(PsB, wave * 16 + l16, ks * 32 + quad * 8);
#pragma unroll
        for (int nt = 0; nt < 4; nt++)
          oB[nt] = __builtin_amdgcn_mfma_f32_16x16x32_bf16(apB, vf[ks][nt],
                                                           oB[nt], 0, 0, 0);
      }
      if (doA) {
#pragma unroll
        for (int ks = 0; ks < 2; ks++) {
          const v8bf apA = FRAG(PsA, wave * 16 + l16, ks * 32 + quad * 8);
#pragma unroll
          for (int nt = 0; nt < 4; nt++)
            oA[nt] = __builtin_amdgcn_mfma_f32_16x16x32_bf16(apA, vf[ks][nt],
                                                             oA[nt], 0, 0, 0);
        }
      }
    }
  }

#pragma unroll
  for (int r = 0; r < 4; r++) {
    float la = lpA[r], lb = lpB[r];
#pragma unroll
    for (int off = 1; off < 16; off <<= 1) {
      la += __shfl_xor(la, off, 16);
      lb += __shfl_xor(lb, off, 16);
    }
    const float ila = 1.0f / la, ilb = 1.0f / lb;
#pragma unroll
    for (int nt = 0; nt < 4; nt++) {
      Y[(rowbase + qa * 64 + wave * 16 + quad * 4 + r) * 1024 + h * 64 + nt * 16 + l16] =
          __float2bfloat16(oA[nt][r] * ila);
      Y[(rowbase + qb * 64 + wave * 16 + quad * 4 + r) * 1024 + h * 64 + nt * 16 + l16] =
          __float2bfloat16(oB[nt][r] * ilb);
    }
  }
}

// ---------------------------------------------------------------------------
extern "C" void kernel_launch(void* const* d_in, const int* in_sizes, int n_in,
                              void* d_out, int out_size, void* d_ws, size_t ws_size,
                              hipStream_t stream)
{
  const float* x  = (const float*)d_in[0];
  const float* Wq = (const float*)d_in[1];
  const float* Wk = (const float*)d_in[2];
  const float* Wv = (const float*)d_in[3];
  const float* Wo = (const float*)d_in[4];
  const float* W1 = (const float*)d_in[5];
  const float* b1 = (const float*)d_in[6];
  const float* W2 = (const float*)d_in[7];
  const float* b2 = (const float*)d_in[8];
  const float* g1 = (const float*)d_in[9];
  const float* g2 = (const float*)d_in[10];

  uint8_t* ws = (uint8_t*)d_ws;
  __hip_bfloat16* WqkvT = (__hip_bfloat16*)(ws + 0);
  __hip_bfloat16* WoT   = (__hip_bfloat16*)(ws + 6291456);
  __hip_bfloat16* W1T   = (__hip_bfloat16*)(ws + 8388608);
  __hip_bfloat16* W2T   = (__hip_bfloat16*)(ws + 16777216);
  float*          x1    = (float*)(ws + 25165824);
  __hip_bfloat16* xn    = (__hip_bfloat16*)(ws + 41943040);
  __hip_bfloat16* Ybuf  = (__hip_bfloat16*)(ws + 41943040);
  __hip_bfloat16* QKV   = (__hip_bfloat16*)(ws + 50331648);
  __hip_bfloat16* VTg   = (__hip_bfloat16*)(ws + 75497472);
  __hip_bfloat16* Hbuf  = (__hip_bfloat16*)(ws + 50331648);

  const dim3 tb(32, 8);
  transpose_w4<<<dim3(32, 32, 4), tb, 0, stream>>>(Wq, Wk, Wv, Wo, WqkvT);
  transpose_w<<<dim3(128, 32), tb, 0, stream>>>(W1, W1T, 1024, 4096, 1024);
  transpose_w<<<dim3(32, 128), tb, 0, stream>>>(W2, W2T, 4096, 1024, 4096);

  rmsnorm_kernel<<<4096, 256, 0, stream>>>(x, g1, xn, nullptr, nullptr);
  // QKV: 256^2 8-phase, grid (12,16) = 192 blocks; XCD patches 3x8
  gemm256<0, 4, 2><<<dim3(12, 16), 512, 0, stream>>>(
      xn, WqkvT, nullptr, QKV, nullptr, 4096, 3072, 1024, 1024);
  transpose_v<<<dim3(64, 64), tb, 0, stream>>>(QKV, VTg);
  attn_kernel<<<512, 256, 0, stream>>>(QKV, VTg, Ybuf);
  // Wo: legacy structure (256^2 grid would be 64 blocks = 1/4 chip)
  gemm_bt<1, 2, 1, 8><<<dim3(8, 64), 256, 0, stream>>>(
      Ybuf, WoT, nullptr, x, nullptr, x1, 4096, 1024, 1024, 1024);
  // rmsnorm2 also pre-initializes d_out = x1 + b2 (split-K atomic target)
  rmsnorm_kernel<<<4096, 256, 0, stream>>>(x1, g2, xn, b2, (float*)d_out);
  // FFN1: 256^2 8-phase, grid (16,16) = 256 blocks (1/CU); XCD patches 4x8
  gemm256<2, 4, 2><<<dim3(16, 16), 512, 0, stream>>>(
      xn, W1T, b1, Hbuf, nullptr, 4096, 4096, 1024, 1024);
  // FFN2: 256^2 8-phase, split-K=4 -> 256 blocks, Ksub=1024; atomics into d_out
  gemm256<4, 4, 2><<<dim3(4, 16, 4), 512, 0, stream>>>(
      Hbuf, W2T, nullptr, nullptr, (float*)d_out, 4096, 1024, 4096, 1024);
}

// Round 2
// 331.664 us; speedup vs baseline: 1.0642x; 1.0642x over previous
//
#include <hip/hip_runtime.h>
#include <hip/hip_bf16.h>
#include <math.h>
#include <stdint.h>

// ---------------------------------------------------------------------------
// Transformer block: x + attn(rms(x,g1)) -> x1 ; x1 + ffn(rms(x1,g2))
// B=2 T=2048 D=1024 H=16 Dh=64 FF=4096. All GEMMs bf16 MFMA 16x16x32.
// R10: gemm256 8-phase REWRITE — R9's version ran at legacy speed because
//  (1) wg_barrier's "memory"-clobber asm made the backend drain vmcnt/lgkmcnt
//      at every phase (counted-vmcnt defeated -> 2-phase behavior), and
//  (2) compiler-visible ds_reads of the DMA-written LDS buffers let alias
//      analysis insert conservative vmcnt(0) before fragment reads.
//  Fix: opaque inline-asm ds_read_b128 on laundered 32-bit LDS addresses,
//  bare s_barrier (no clobbers), explicit lgkmcnt(0)+sched_barrier(0) before
//  each MFMA cluster (rule #18), counted vmcnt(4) once per K-tile, LDS base
//  escaped via asm so DMA stores can't be DCE'd.
//  FFN2 reverted to R8 legacy split-K=2 (R9's split-K=4 atomics: 83.6us, regress).
// LDS tiles use XOR-swizzled 16B chunks (chunk j of row r lives at j^(r&7));
// rocprof shows SQ_LDS_BANK_CONFLICT == 0 for this scheme.
// ---------------------------------------------------------------------------

typedef __bf16 v8bf  __attribute__((ext_vector_type(8)));
typedef float  v4f   __attribute__((ext_vector_type(4)));

#define T_SEQ 2048
#define EXP2F(x) __builtin_amdgcn_exp2f(x)  // v_exp_f32 (2^x)

// swizzled fragment read (compiler path, used by legacy gemm + attn)
#define FRAG(base, R, ko) \
  (*(const v8bf*)((base) + (R) * 64 + (((((ko) >> 3) ^ ((R) & 7))) << 3)))

__device__ __forceinline__ void async_ld16(const void* g, void* l) {
  // global -> LDS direct, 16B/lane. LDS dest is wave-uniform base + lane*16.
  __builtin_amdgcn_global_load_lds(
      (const __attribute__((address_space(1))) uint32_t*)g,
      (__attribute__((address_space(3))) uint32_t*)l, 16, 0, 0);
}

// 32-bit LDS byte offset of a generic pointer to __shared__ memory
__device__ __forceinline__ uint32_t lds_addr(const void* p) {
  return (uint32_t)(uintptr_t)(const __attribute__((address_space(3))) void*)p;
}

// opaque LDS read: compiler cannot alias-analyze (no memory operand) ->
// no auto-inserted vmcnt/lgkmcnt; ordering is manual (barriers + WAITL).
__device__ __forceinline__ v8bf ds_read16(uint32_t a) {
  v8bf r;
  asm volatile("ds_read_b128 %0, %1" : "=v"(r) : "v"(a));
  return r;
}

#define WAITL                                  \
  do {                                         \
    asm volatile("s_waitcnt lgkmcnt(0)");      \
    __builtin_amdgcn_sched_barrier(0);         \
  } while (0)

// ---------------- 4x weight transpose (Wq,Wk,Wv,Wo) fused ------------------
__global__ __launch_bounds__(256) void transpose_w4(
    const float* __restrict__ Wq, const float* __restrict__ Wk,
    const float* __restrict__ Wv, const float* __restrict__ Wo,
    __hip_bfloat16* __restrict__ out)
{
  __shared__ float tile[32][33];
  const int z = blockIdx.z;
  const float* W = z == 0 ? Wq : z == 1 ? Wk : z == 2 ? Wv : Wo;
  const int n0 = blockIdx.x * 32, k0 = blockIdx.y * 32;
  const int tx = threadIdx.x, ty = threadIdx.y;  // 32 x 8
#pragma unroll
  for (int i = 0; i < 32; i += 8)
    tile[ty + i][tx] = W[(size_t)(k0 + ty + i) * 1024 + n0 + tx];
  __syncthreads();
  __hip_bfloat16* o = out + (size_t)z * 1024 * 1024;
#pragma unroll
  for (int i = 0; i < 32; i += 8)
    o[(size_t)(n0 + ty + i) * 1024 + k0 + tx] = __float2bfloat16(tile[tx][ty + i]);
}

// ---------------- generic weight transpose ----------------------------------
__global__ __launch_bounds__(256) void transpose_w(
    const float* __restrict__ W, __hip_bfloat16* __restrict__ WT,
    int K, int N, int ldo)
{
  __shared__ float tile[32][33];
  const int n0 = blockIdx.x * 32, k0 = blockIdx.y * 32;
  const int tx = threadIdx.x, ty = threadIdx.y;  // 32 x 8
#pragma unroll
  for (int i = 0; i < 32; i += 8)
    tile[ty + i][tx] = W[(size_t)(k0 + ty + i) * N + n0 + tx];
  __syncthreads();
#pragma unroll
  for (int i = 0; i < 32; i += 8)
    WT[(size_t)(n0 + ty + i) * ldo + k0 + tx] = __float2bfloat16(tile[tx][ty + i]);
}

// ---------------- V transpose: QKV V-part -> VTg[b][h][d][t] ---------------
__global__ __launch_bounds__(256) void transpose_v(
    const __hip_bfloat16* __restrict__ QKV, __hip_bfloat16* __restrict__ VTg)
{
  __shared__ float tile[32][33];
  const int t0 = blockIdx.x * 32;
  const int bh = blockIdx.y >> 1;
  const int dt = (blockIdx.y & 1) * 32;
  const int b = bh >> 4, h = bh & 15;
  const int tx = threadIdx.x, ty = threadIdx.y;  // 32 x 8
#pragma unroll
  for (int i = 0; i < 32; i += 8)
    tile[ty + i][tx] = __bfloat162float(
        QKV[(size_t)(b * T_SEQ + t0 + ty + i) * 3072 + 2048 + h * 64 + dt + tx]);
  __syncthreads();
#pragma unroll
  for (int i = 0; i < 32; i += 8)
    VTg[((size_t)bh * 64 + dt + ty + i) * T_SEQ + t0 + tx] =
        __float2bfloat16(tile[tx][ty + i]);
}

// ---------------- RMSNorm (fp32 in -> bf16 out, optional d_out init) -------
__global__ __launch_bounds__(256) void rmsnorm_kernel(
    const float* __restrict__ x, const float* __restrict__ g,
    __hip_bfloat16* __restrict__ out,
    const float* __restrict__ bias, float* __restrict__ dinit)
{
  const int row = blockIdx.x;
  const int t = threadIdx.x;
  const float4 v = ((const float4*)(x + (size_t)row * 1024))[t];
  float ss = v.x * v.x + v.y * v.y + v.z * v.z + v.w * v.w;
#pragma unroll
  for (int off = 32; off; off >>= 1) ss += __shfl_xor(ss, off, 64);
  __shared__ float red[4];
  if ((t & 63) == 0) red[t >> 6] = ss;
  __syncthreads();
  ss = red[0] + red[1] + red[2] + red[3];
  const float rs = rsqrtf(ss * (1.0f / 1024.0f) + 1e-6f);
  const float4 gv = ((const float4*)g)[t];
  __hip_bfloat16* o = out + (size_t)row * 1024 + t * 4;
  o[0] = __float2bfloat16(v.x * rs * gv.x);
  o[1] = __float2bfloat16(v.y * rs * gv.y);
  o[2] = __float2bfloat16(v.z * rs * gv.z);
  o[3] = __float2bfloat16(v.w * rs * gv.w);
  if (dinit) {
    const float4 bv = ((const float4*)bias)[t];
    float4 d;
    d.x = v.x + bv.x; d.y = v.y + bv.y; d.z = v.z + bv.z; d.w = v.w + bv.w;
    ((float4*)(dinit + (size_t)row * 1024))[t] = d;
  }
}

// ---------------- legacy GEMM (Wo, FFN2): C = A @ BT^T (+epilogue) ---------
// MODE 1: outf = resid + C   MODE 4: atomicAdd(outf, C)
template <int MODE, int MT, int PX, int PY>
__global__ __launch_bounds__(256, 2) void gemm_bt(
    const __hip_bfloat16* __restrict__ A,
    const __hip_bfloat16* __restrict__ BT,
    const float* __restrict__ bias,
    const float* __restrict__ resid,
    __hip_bfloat16* __restrict__ outb,
    float* __restrict__ outf,
    int M, int N, int K, int Ksub)
{
  __shared__ __align__(16) __hip_bfloat16 As[32 * MT * 64];
  __shared__ __align__(16) __hip_bfloat16 Bs[128 * 64];
  const int tid = threadIdx.x;
  const int wave = tid >> 6, lane = tid & 63;
  const int quad = lane >> 4, l16 = lane & 15;

  int bx = blockIdx.x, by = blockIdx.y;
  {
    const int id = by * gridDim.x + bx;
    const int k = id & 7, s = id >> 3;
    const int pw = gridDim.x / PX, ph = gridDim.y / PY;
    bx = (k % PX) * pw + (s % pw);
    by = (k / PX) * ph + (s / pw);
  }
  const int m0 = by * (32 * MT), n0 = bx * 128;
  const size_t kb = (size_t)blockIdx.z * Ksub;
  const int wr = (wave >> 1) * (16 * MT), wc = (wave & 1) * 64;
  const int lrow = lane >> 3;
  const int scol = ((lane & 7) ^ lrow) * 8;

  v4f acc[MT][4];
#pragma unroll
  for (int i = 0; i < MT; i++)
#pragma unroll
    for (int j = 0; j < 4; j++)
#pragma unroll
      for (int c = 0; c < 4; c++) acc[i][j][c] = 0.0f;

  for (int k0 = 0; k0 < Ksub; k0 += 64) {
#pragma unroll
    for (int i = 0; i < MT + 4; i++) {
      const int c = wave * (MT + 4) + i;
      if (c < 4 * MT) {
        async_ld16(A + (size_t)(m0 + c * 8 + lrow) * K + kb + k0 + scol, As + c * 512);
      } else {
        const int cb = c - 4 * MT;
        async_ld16(BT + (size_t)(n0 + cb * 8 + lrow) * K + kb + k0 + scol,
                   Bs + cb * 512);
      }
    }
    __syncthreads();
#pragma unroll
    for (int ks = 0; ks < 64; ks += 32) {
      v8bf af[MT], bfr[4];
#pragma unroll
      for (int mt = 0; mt < MT; mt++)
        af[mt] = FRAG(As, wr + mt * 16 + l16, ks + quad * 8);
#pragma unroll
      for (int nt = 0; nt < 4; nt++)
        bfr[nt] = FRAG(Bs, wc + nt * 16 + l16, ks + quad * 8);
#pragma unroll
      for (int mt = 0; mt < MT; mt++)
#pragma unroll
        for (int nt = 0; nt < 4; nt++)
          acc[mt][nt] = __builtin_amdgcn_mfma_f32_16x16x32_bf16(
              af[mt], bfr[nt], acc[mt][nt], 0, 0, 0);
    }
    __syncthreads();
  }

#pragma unroll
  for (int mt = 0; mt < MT; mt++) {
#pragma unroll
    for (int r = 0; r < 4; r++) {
      const int gm = m0 + wr + mt * 16 + quad * 4 + r;
#pragma unroll
      for (int nt = 0; nt < 4; nt++) {
        const int gn = n0 + wc + nt * 16 + l16;
        float v = acc[mt][nt][r];
        if (MODE == 0) {
          outb[(size_t)gm * N + gn] = __float2bfloat16(v);
        } else if (MODE == 1) {
          outf[(size_t)gm * N + gn] = resid[(size_t)gm * N + gn] + v;
        } else if (MODE == 2) {
          v += bias[gn];
          const float u = 0.7978845608f * (v + 0.044715f * v * v * v);
          const float e = EXP2F(u * 2.885390082f);
          const float th = 1.0f - 2.0f * __builtin_amdgcn_rcpf(e + 1.0f);
          v = 0.5f * v * (1.0f + th);
          outb[(size_t)gm * N + gn] = __float2bfloat16(v);
        } else {
          atomicAdd(&outf[(size_t)gm * N + gn], v);
        }
      }
    }
  }
}

// ---------------- GEMM 256x256 8-phase (counted-vmcnt schedule) ------------
// C = A @ BT^T. A [M][K] bf16, BT [N][K] bf16. BM=BN=256, BK=64, 512 thr.
// 8 waves (2M x 4N); per-wave 128x64 output as STRIDED halves:
//   rows: mh*128 + wm*64 + (0..63)   cols: nh*128 + wn*32 + (0..31)
// Per K-tile, 4 phases, quadrant order (0,0),(0,1),(1,1),(1,0); each phase:
//   { asm ds_read frags | issue 1 half-tile stage | s_barrier |
//     lgkmcnt(0)+sched_barrier | setprio(1) 16xMFMA setprio(0) |
//     [P3: s_waitcnt vmcnt(4)] | s_barrier }
// Stage ledger (steady state), half-stages of tile t+1/t+2 (2 loads/wave):
//   P0(t): A1(t+1)  P1(t): B0(t+1)  P2(t): A0(t+2)  P3(t): B1(t+2)
//   wait@P3(t): 12 outstanding -> vmcnt(4) drains 8 oldest = ALL of t+1,
//   leaves t+2's {A0,B1}. Tail degrades vmcnt(4)->vmcnt(0)->none.
// ds_reads are OPAQUE asm on laundered 32-bit LDS addrs: no auto-waitcnts.
// MODE 0: outb=bf16(C)   MODE 2: outb=bf16(gelu(C+bias))
template <int MODE, int PX, int PY>
__global__ __launch_bounds__(512, 2) void gemm256(
    const __hip_bfloat16* __restrict__ A,
    const __hip_bfloat16* __restrict__ BT,
    const float* __restrict__ bias,
    __hip_bfloat16* __restrict__ outb,
    float* __restrict__ outf,
    int M, int N, int K, int Ksub)
{
  __shared__ __align__(16) __hip_bfloat16 As[2 * 256 * 64];  // 64 KiB
  __shared__ __align__(16) __hip_bfloat16 Bs[2 * 256 * 64];  // 64 KiB
  (void)M; (void)outf;
  const int tid = threadIdx.x;
  const int wave = tid >> 6, lane = tid & 63;
  const int quad = lane >> 4, l16 = lane & 15;
  const int wm = wave >> 2, wn = wave & 3;
  const int lrow = lane >> 3, scol = ((lane & 7) ^ lrow) * 8;

  int bx = blockIdx.x, by = blockIdx.y;
  {
    const int id = by * gridDim.x + bx;
    const int k = id & 7, s = id >> 3;
    const int pw = gridDim.x / PX, ph = gridDim.y / PY;
    bx = (k % PX) * pw + (s % pw);
    by = (k / PX) * ph + (s / pw);
  }
  const int m0 = by * 256, n0 = bx * 256;
  const size_t kb = (size_t)blockIdx.z * Ksub;
  const int NT = Ksub >> 6;
  const int cg = wave * 2;  // this wave's 2 row-group slots (of 16 per half)

  // laundered LDS bases: escapes the arrays (DMA stores not DCE-able) and
  // breaks alias links between ds_read asm and global_load_lds.
  uint32_t AsL = lds_addr(As), BsL = lds_addr(Bs);
  asm volatile("" : "+s"(AsL), "+s"(BsL));

  // per-thread fragment read addresses (byte): row*128 + swizzled chunk*16.
  // chunk(ks) = ((ks*4+quad) ^ (l16&7)); rows: A mh*128+wm*64+mt*16+l16,
  //                                      B nh*128+wn*32+nt*16+l16.
  const uint32_t cx0 = (uint32_t)(((0 * 4 + quad) ^ (l16 & 7)) * 16);
  const uint32_t cx1 = (uint32_t)(((1 * 4 + quad) ^ (l16 & 7)) * 16);
  const uint32_t aB0 = AsL + (uint32_t)((wm * 64 + l16) * 128) + cx0;
  const uint32_t aB1 = AsL + (uint32_t)((wm * 64 + l16) * 128) + cx1;
  const uint32_t bB0 = BsL + (uint32_t)((wn * 32 + l16) * 128) + cx0;
  const uint32_t bB1 = BsL + (uint32_t)((wn * 32 + l16) * 128) + cx1;

  auto stageA = [&](int h, int tt) {
#pragma unroll
    for (int j = 0; j < 2; j++) {
      const int rg = cg + j;
      async_ld16(A + (size_t)(m0 + h * 128 + rg * 8 + lrow) * K + kb + tt * 64 + scol,
                 As + ((tt & 1) * 16384 + (h * 128 + rg * 8) * 64));
    }
  };
  auto stageB = [&](int h, int tt) {
#pragma unroll
    for (int j = 0; j < 2; j++) {
      const int rg = cg + j;
      async_ld16(BT + (size_t)(n0 + h * 128 + rg * 8 + lrow) * K + kb + tt * 64 + scol,
                 Bs + ((tt & 1) * 16384 + (h * 128 + rg * 8) * 64));
    }
  };

  v4f acc[8][4];
#pragma unroll
  for (int i = 0; i < 8; i++)
#pragma unroll
    for (int j = 0; j < 4; j++)
#pragma unroll
      for (int c = 0; c < 4; c++) acc[i][j][c] = 0.0f;

  // prologue: tile0 {A0,B0,B1,A1} + tile1 {A0,B1}; drain tile0 (8 of 12)
  stageA(0, 0); stageB(0, 0); stageB(1, 0); stageA(1, 0);
  if (NT > 1) {
    stageA(0, 1); stageB(1, 1);
    asm volatile("s_waitcnt vmcnt(4)");
  } else {
    asm volatile("s_waitcnt vmcnt(0)");
  }
  __builtin_amdgcn_s_barrier();

#define RA(mh)                                                      \
  _Pragma("unroll") for (int mt = 0; mt < 4; mt++) {                \
    af[mt][0] = ds_read16(a0a + (mh) * 16384 + mt * 2048);          \
    af[mt][1] = ds_read16(a1a + (mh) * 16384 + mt * 2048);          \
  }
#define RB(dst, nh)                                                 \
  _Pragma("unroll") for (int nt = 0; nt < 2; nt++) {                \
    dst[nt][0] = ds_read16(b0a + (nh) * 16384 + nt * 2048);         \
    dst[nt][1] = ds_read16(b1a + (nh) * 16384 + nt * 2048);         \
  }
#define MM16(mh, bsrc, nh)                                                  \
  __builtin_amdgcn_s_setprio(1);                                            \
  _Pragma("unroll") for (int mt = 0; mt < 4; mt++)                          \
      _Pragma("unroll") for (int nt = 0; nt < 2; nt++)                      \
          _Pragma("unroll") for (int ks = 0; ks < 2; ks++)                  \
              acc[(mh) * 4 + mt][(nh) * 2 + nt] =                           \
                  __builtin_amdgcn_mfma_f32_16x16x32_bf16(                  \
                      af[mt][ks], bsrc[nt][ks],                             \
                      acc[(mh) * 4 + mt][(nh) * 2 + nt], 0, 0, 0);          \
  __builtin_amdgcn_s_setprio(0)

  for (int t = 0; t < NT; ++t) {
    const uint32_t bsel = (uint32_t)((t & 1) * 32768);
    const uint32_t a0a = aB0 + bsel, a1a = aB1 + bsel;
    const uint32_t b0a = bB0 + bsel, b1a = bB1 + bsel;
    v8bf af[4][2], b0[2][2], b1[2][2];
    // ---- P0: quadrant (0,0)
    RA(0); RB(b0, 0);
    if (t + 1 < NT) stageA(1, t + 1);
    __builtin_amdgcn_s_barrier();
    WAITL;
    MM16(0, b0, 0);
    __builtin_amdgcn_s_barrier();
    // ---- P1: quadrant (0,1)
    RB(b1, 1);
    if (t + 1 < NT) stageB(0, t + 1);
    __builtin_amdgcn_s_barrier();
    WAITL;
    MM16(0, b1, 1);
    __builtin_amdgcn_s_barrier();
    // ---- P2: quadrant (1,1)
    RA(1);
    if (t + 2 < NT) stageA(0, t + 2);
    __builtin_amdgcn_s_barrier();
    WAITL;
    MM16(1, b1, 1);
    __builtin_amdgcn_s_barrier();
    // ---- P3: quadrant (1,0)
    if (t + 2 < NT) stageB(1, t + 2);
    WAITL;  // b0 frags already waited at P0; cheap re-wait keeps rule #18 local
    MM16(1, b0, 0);
    if (t + 2 < NT) {
      asm volatile("s_waitcnt vmcnt(4)");  // drain ALL of tile t+1
    } else if (t + 1 < NT) {
      asm volatile("s_waitcnt vmcnt(0)");  // tail drain
    }
    __builtin_amdgcn_s_barrier();
  }
#undef RA
#undef RB
#undef MM16

  // epilogue: C/D layout col=lane&15, row=quad*4+reg
#pragma unroll
  for (int ni = 0; ni < 4; ni++) {
    const int gn = n0 + (ni >> 1) * 128 + wn * 32 + (ni & 1) * 16 + l16;
    float bcol = 0.0f;
    if (MODE == 2) bcol = bias[gn];
#pragma unroll
    for (int mi = 0; mi < 8; mi++) {
      const int gmb = m0 + (mi >> 2) * 128 + wm * 64 + (mi & 3) * 16 + quad * 4;
#pragma unroll
      for (int r = 0; r < 4; r++) {
        float v = acc[mi][ni][r];
        const size_t idx = (size_t)(gmb + r) * N + gn;
        if (MODE == 0) {
          outb[idx] = __float2bfloat16(v);
        } else {
          v += bcol;
          // tanh-GELU (max |err| ~1e-3 in h -> <1e-3 in final output)
          const float u = 0.7978845608f * (v + 0.044715f * v * v * v);
          const float e = EXP2F(u * 2.885390082f);  // exp(2u)
          const float th = 1.0f - 2.0f * __builtin_amdgcn_rcpf(e + 1.0f);
          v = 0.5f * v * (1.0f + th);
          outb[idx] = __float2bfloat16(v);
        }
      }
    }
  }
}

// ---------------- flash attention (causal, no-max exp2 softmax) ------------
__global__ __launch_bounds__(256, 2) void attn_kernel(
    const __hip_bfloat16* __restrict__ QKV,
    const __hip_bfloat16* __restrict__ VTg,
    __hip_bfloat16* __restrict__ Y)
{
  __shared__ __align__(16) __hip_bfloat16 Ks[2 * 64 * 64];
  __shared__ __align__(16) __hip_bfloat16 Vs[2 * 64 * 64];
  __shared__ __align__(16) __hip_bfloat16 PsA[64 * 64];
  __shared__ __align__(16) __hip_bfloat16 PsB[64 * 64];

  const int tid = threadIdx.x;
  const int wave = tid >> 6, lane = tid & 63;
  const int quad = lane >> 4, l16 = lane & 15;
  const int blk = blockIdx.x;
  const int p = blk & 15, h = (blk >> 4) & 15, b = blk >> 8;
  const int qa = p, qb = 31 - p, kmax = qb;
  const size_t rowbase = (size_t)b * T_SEQ;
  const size_t vbase = (size_t)(b * 16 + h) * 64;
  const int lrow = lane >> 3, scol = ((lane & 7) ^ (lane >> 3)) * 8;

  const float QSC = 0.125f * 1.44269504f;
  v8bf aqA[2], aqB[2];
#pragma unroll
  for (int ks = 0; ks < 2; ks++) {
    v8bf q = *(const v8bf*)(QKV + (rowbase + qa * 64 + wave * 16 + l16) * 3072 +
                            h * 64 + ks * 32 + quad * 8);
#pragma unroll
    for (int j = 0; j < 8; j++) aqA[ks][j] = (__bf16)((float)q[j] * QSC);
    q = *(const v8bf*)(QKV + (rowbase + qb * 64 + wave * 16 + l16) * 3072 +
                       h * 64 + ks * 32 + quad * 8);
#pragma unroll
    for (int j = 0; j < 8; j++) aqB[ks][j] = (__bf16)((float)q[j] * QSC);
  }

  v4f oA[4], oB[4];
  float lpA[4], lpB[4];
#pragma unroll
  for (int i = 0; i < 4; i++) {
    lpA[i] = 0.0f; lpB[i] = 0.0f;
#pragma unroll
    for (int c = 0; c < 4; c++) { oA[i][c] = 0.0f; oB[i][c] = 0.0f; }
  }

  auto stage = [&](int kt, int buf) {
#pragma unroll
    for (int i = 0; i < 2; i++) {
      const int r8 = i * 32 + wave * 8;
      const int rr = r8 + lrow;
      async_ld16(QKV + (rowbase + kt * 64 + rr) * 3072 + 1024 + h * 64 + scol,
                 Ks + buf * 4096 + r8 * 64);
      async_ld16(VTg + (vbase + rr) * T_SEQ + kt * 64 + scol,
                 Vs + buf * 4096 + r8 * 64);
    }
  };
  stage(0, 0);

  auto softmax_store = [&](v4f s[4], float lp[4], __hip_bfloat16* Ps, bool diag) {
    if (diag) {
#pragma unroll
      for (int nt = 0; nt < 4; nt++) {
        const int colr = nt * 16 + l16;
#pragma unroll
        for (int r = 0; r < 4; r++)
          if (colr > wave * 16 + quad * 4 + r) s[nt][r] = -30000.0f;
      }
    }
#pragma unroll
    for (int r = 0; r < 4; r++) {
      const int row = wave * 16 + quad * 4 + r;
      const int rsw = (quad * 4 + r) & 7;
#pragma unroll
      for (int nt = 0; nt < 4; nt++) {
        const float e = EXP2F(s[nt][r]);
        lp[r] += e;
        const int chunk = (nt * 2 + (l16 >> 3)) ^ rsw;
        Ps[row * 64 + (chunk << 3) + (l16 & 7)] = __float2bfloat16(e);
      }
    }
  };

  for (int kt = 0; kt <= kmax; kt++) {
    __syncthreads();
    if (kt < kmax) stage(kt + 1, (kt + 1) & 1);
    const __hip_bfloat16* Kb = Ks + (kt & 1) * 4096;
    const __hip_bfloat16* Vb = Vs + (kt & 1) * 4096;
    const bool doA = (kt <= qa);

    {
      v8bf kf[2][4];
#pragma unroll
      for (int ks = 0; ks < 2; ks++)
#pragma unroll
        for (int nt = 0; nt < 4; nt++)
          kf[ks][nt] = FRAG(Kb, nt * 16 + l16, ks * 32 + quad * 8);

      v4f sB[4];
#pragma unroll
      for (int nt = 0; nt < 4; nt++)
#pragma unroll
        for (int c = 0; c < 4; c++) sB[nt][c] = 0.0f;
#pragma unroll
      for (int ks = 0; ks < 2; ks++)
#pragma unroll
        for (int nt = 0; nt < 4; nt++)
          sB[nt] = __builtin_amdgcn_mfma_f32_16x16x32_bf16(aqB[ks], kf[ks][nt],
                                                           sB[nt], 0, 0, 0);
      softmax_store(sB, lpB, PsB, kt == qb);

      if (doA) {
        v4f sA[4];
#pragma unroll
        for (int nt = 0; nt < 4; nt++)
#pragma unroll
          for (int c = 0; c < 4; c++) sA[nt][c] = 0.0f;
#pragma unroll
        for (int ks = 0; ks < 2; ks++)
#pragma unroll
          for (int nt = 0; nt < 4; nt++)
            sA[nt] = __builtin_amdgcn_mfma_f32_16x16x32_bf16(aqA[ks], kf[ks][nt],
                                                             sA[nt], 0, 0, 0);
        softmax_store(sA, lpA, PsA, kt == qa);
      }
    }

    {
      v8bf vf[2][4];
#pragma unroll
      for (int ks = 0; ks < 2; ks++)
#pragma unroll
        for (int nt = 0; nt < 4; nt++)
          vf[ks][nt] = FRAG(Vb, nt * 16 + l16, ks * 32 + quad * 8);
#pragma unroll
      for (int ks = 0; ks < 2; ks++) {
        const v8bf apB = FRAG(PsB, wave * 16 + l16, ks * 32 + quad * 8);
#pragma unroll
        for (int nt = 0; nt < 4; nt++)
          oB[nt] = __builtin_amdgcn_mfma_f32_16x16x32_bf16(apB, vf[ks][nt],
                                                           oB[nt], 0, 0, 0);
      }
      if (doA) {
#pragma unroll
        for (int ks = 0; ks < 2; ks++) {
          const v8bf apA = FRAG(PsA, wave * 16 + l16, ks * 32 + quad * 8);
#pragma unroll
          for (int nt = 0; nt < 4; nt++)
            oA[nt] = __builtin_amdgcn_mfma_f32_16x16x32_bf16(apA, vf[ks][nt],
                                                             oA[nt], 0, 0, 0);
        }
      }
    }
  }

#pragma unroll
  for (int r = 0; r < 4; r++) {
    float la = lpA[r], lb = lpB[r];
#pragma unroll
    for (int off = 1; off < 16; off <<= 1) {
      la += __shfl_xor(la, off, 16);
      lb += __shfl_xor(lb, off, 16);
    }
    const float ila = 1.0f / la, ilb = 1.0f / lb;
#pragma unroll
    for (int nt = 0; nt < 4; nt++) {
      Y[(rowbase + qa * 64 + wave * 16 + quad * 4 + r) * 1024 + h * 64 + nt * 16 + l16] =
          __float2bfloat16(oA[nt][r] * ila);
      Y[(rowbase + qb * 64 + wave * 16 + quad * 4 + r) * 1024 + h * 64 + nt * 16 + l16] =
          __float2bfloat16(oB[nt][r] * ilb);
    }
  }
}

// ---------------------------------------------------------------------------
extern "C" void kernel_launch(void* const* d_in, const int* in_sizes, int n_in,
                              void* d_out, int out_size, void* d_ws, size_t ws_size,
                              hipStream_t stream)
{
  const float* x  = (const float*)d_in[0];
  const float* Wq = (const float*)d_in[1];
  const float* Wk = (const float*)d_in[2];
  const float* Wv = (const float*)d_in[3];
  const float* Wo = (const float*)d_in[4];
  const float* W1 = (const float*)d_in[5];
  const float* b1 = (const float*)d_in[6];
  const float* W2 = (const float*)d_in[7];
  const float* b2 = (const float*)d_in[8];
  const float* g1 = (const float*)d_in[9];
  const float* g2 = (const float*)d_in[10];

  uint8_t* ws = (uint8_t*)d_ws;
  __hip_bfloat16* WqkvT = (__hip_bfloat16*)(ws + 0);
  __hip_bfloat16* WoT   = (__hip_bfloat16*)(ws + 6291456);
  __hip_bfloat16* W1T   = (__hip_bfloat16*)(ws + 8388608);
  __hip_bfloat16* W2T   = (__hip_bfloat16*)(ws + 16777216);
  float*          x1    = (float*)(ws + 25165824);
  __hip_bfloat16* xn    = (__hip_bfloat16*)(ws + 41943040);
  __hip_bfloat16* Ybuf  = (__hip_bfloat16*)(ws + 41943040);
  __hip_bfloat16* QKV   = (__hip_bfloat16*)(ws + 50331648);
  __hip_bfloat16* VTg   = (__hip_bfloat16*)(ws + 75497472);
  __hip_bfloat16* Hbuf  = (__hip_bfloat16*)(ws + 50331648);

  const dim3 tb(32, 8);
  transpose_w4<<<dim3(32, 32, 4), tb, 0, stream>>>(Wq, Wk, Wv, Wo, WqkvT);
  transpose_w<<<dim3(128, 32), tb, 0, stream>>>(W1, W1T, 1024, 4096, 1024);
  transpose_w<<<dim3(32, 128), tb, 0, stream>>>(W2, W2T, 4096, 1024, 4096);

  rmsnorm_kernel<<<4096, 256, 0, stream>>>(x, g1, xn, nullptr, nullptr);
  // QKV: 256^2 8-phase, grid (12,16) = 192 blocks; XCD patches 3x8
  gemm256<0, 4, 2><<<dim3(12, 16), 512, 0, stream>>>(
      xn, WqkvT, nullptr, QKV, nullptr, 4096, 3072, 1024, 1024);
  transpose_v<<<dim3(64, 64), tb, 0, stream>>>(QKV, VTg);
  attn_kernel<<<512, 256, 0, stream>>>(QKV, VTg, Ybuf);
  // Wo: legacy structure (small N; 256^2 grid would be 64 blocks)
  gemm_bt<1, 2, 1, 8><<<dim3(8, 64), 256, 0, stream>>>(
      Ybuf, WoT, nullptr, x, nullptr, x1, 4096, 1024, 1024, 1024);
  // rmsnorm2 also pre-initializes d_out = x1 + b2 (split-K atomic target)
  rmsnorm_kernel<<<4096, 256, 0, stream>>>(x1, g2, xn, b2, (float*)d_out);
  // FFN1: 256^2 8-phase, grid (16,16) = 256 blocks (1/CU); XCD patches 4x8
  gemm256<2, 4, 2><<<dim3(16, 16), 512, 0, stream>>>(
      xn, W1T, b1, Hbuf, nullptr, 4096, 4096, 1024, 1024);
  // FFN2: legacy split-K=2, MT=2 (R6/R8 best): 1024 blocks (4/CU);
  // partials atomicAdd into pre-initialized d_out
  gemm_bt<4, 2, 1, 8><<<dim3(8, 64, 2), 256, 0, stream>>>(
      Hbuf, W2T, nullptr, nullptr, nullptr, (float*)d_out, 4096, 1024, 4096, 2048);
}

// Round 3
// 324.429 us; speedup vs baseline: 1.0879x; 1.0223x over previous
//
#include <hip/hip_runtime.h>
#include <hip/hip_bf16.h>
#include <math.h>
#include <stdint.h>

// ---------------------------------------------------------------------------
// Transformer block: x + attn(rms(x,g1)) -> x1 ; x1 + ffn(rms(x1,g2))
// B=2 T=2048 D=1024 H=16 Dh=64 FF=4096. All GEMMs bf16 MFMA 16x16x32.
// R11: minimal-delta experiment on gemm256. R9 (clobber barriers) and R10
//  (opaque volatile-asm ds_reads + sched_barrier fences) both ran at legacy
//  ~600 TF: R9's clobbers forced waitcnt drains; R10's volatile asm made the
//  whole phase un-schedulable (compiler can't interleave reads/MFMA/stage).
//  R11 = the verified m201 configuration exactly: compiler-visible FRAG
//  ds_reads (compiler emits fine-grained lgkmcnt itself), bare s_barrier,
//  inline asm ONLY for the counted s_waitcnt vmcnt(4/0). Everything else
//  (stage ledger, swizzle, quadrant order, setprio, grids) identical to R10
//  so the total-time delta isolates this one variable.
// LDS tiles use XOR-swizzled 16B chunks (chunk j of row r lives at j^(r&7));
// rocprof shows SQ_LDS_BANK_CONFLICT == 0 for this scheme.
// ---------------------------------------------------------------------------

typedef __bf16 v8bf  __attribute__((ext_vector_type(8)));
typedef float  v4f   __attribute__((ext_vector_type(4)));

#define T_SEQ 2048
#define EXP2F(x) __builtin_amdgcn_exp2f(x)  // v_exp_f32 (2^x)

// swizzled fragment read: row R, k-elem offset ko (multiple of 8)
#define FRAG(base, R, ko) \
  (*(const v8bf*)((base) + (R) * 64 + (((((ko) >> 3) ^ ((R) & 7))) << 3)))

__device__ __forceinline__ void async_ld16(const void* g, void* l) {
  // global -> LDS direct, 16B/lane. LDS dest is wave-uniform base + lane*16.
  __builtin_amdgcn_global_load_lds(
      (const __attribute__((address_space(1))) uint32_t*)g,
      (__attribute__((address_space(3))) uint32_t*)l, 16, 0, 0);
}

// ---------------- 4x weight transpose (Wq,Wk,Wv,Wo) fused ------------------
__global__ __launch_bounds__(256) void transpose_w4(
    const float* __restrict__ Wq, const float* __restrict__ Wk,
    const float* __restrict__ Wv, const float* __restrict__ Wo,
    __hip_bfloat16* __restrict__ out)
{
  __shared__ float tile[32][33];
  const int z = blockIdx.z;
  const float* W = z == 0 ? Wq : z == 1 ? Wk : z == 2 ? Wv : Wo;
  const int n0 = blockIdx.x * 32, k0 = blockIdx.y * 32;
  const int tx = threadIdx.x, ty = threadIdx.y;  // 32 x 8
#pragma unroll
  for (int i = 0; i < 32; i += 8)
    tile[ty + i][tx] = W[(size_t)(k0 + ty + i) * 1024 + n0 + tx];
  __syncthreads();
  __hip_bfloat16* o = out + (size_t)z * 1024 * 1024;
#pragma unroll
  for (int i = 0; i < 32; i += 8)
    o[(size_t)(n0 + ty + i) * 1024 + k0 + tx] = __float2bfloat16(tile[tx][ty + i]);
}

// ---------------- generic weight transpose ----------------------------------
__global__ __launch_bounds__(256) void transpose_w(
    const float* __restrict__ W, __hip_bfloat16* __restrict__ WT,
    int K, int N, int ldo)
{
  __shared__ float tile[32][33];
  const int n0 = blockIdx.x * 32, k0 = blockIdx.y * 32;
  const int tx = threadIdx.x, ty = threadIdx.y;  // 32 x 8
#pragma unroll
  for (int i = 0; i < 32; i += 8)
    tile[ty + i][tx] = W[(size_t)(k0 + ty + i) * N + n0 + tx];
  __syncthreads();
#pragma unroll
  for (int i = 0; i < 32; i += 8)
    WT[(size_t)(n0 + ty + i) * ldo + k0 + tx] = __float2bfloat16(tile[tx][ty + i]);
}

// ---------------- V transpose: QKV V-part -> VTg[b][h][d][t] ---------------
__global__ __launch_bounds__(256) void transpose_v(
    const __hip_bfloat16* __restrict__ QKV, __hip_bfloat16* __restrict__ VTg)
{
  __shared__ float tile[32][33];
  const int t0 = blockIdx.x * 32;
  const int bh = blockIdx.y >> 1;
  const int dt = (blockIdx.y & 1) * 32;
  const int b = bh >> 4, h = bh & 15;
  const int tx = threadIdx.x, ty = threadIdx.y;  // 32 x 8
#pragma unroll
  for (int i = 0; i < 32; i += 8)
    tile[ty + i][tx] = __bfloat162float(
        QKV[(size_t)(b * T_SEQ + t0 + ty + i) * 3072 + 2048 + h * 64 + dt + tx]);
  __syncthreads();
#pragma unroll
  for (int i = 0; i < 32; i += 8)
    VTg[((size_t)bh * 64 + dt + ty + i) * T_SEQ + t0 + tx] =
        __float2bfloat16(tile[tx][ty + i]);
}

// ---------------- RMSNorm (fp32 in -> bf16 out, optional d_out init) -------
__global__ __launch_bounds__(256) void rmsnorm_kernel(
    const float* __restrict__ x, const float* __restrict__ g,
    __hip_bfloat16* __restrict__ out,
    const float* __restrict__ bias, float* __restrict__ dinit)
{
  const int row = blockIdx.x;
  const int t = threadIdx.x;
  const float4 v = ((const float4*)(x + (size_t)row * 1024))[t];
  float ss = v.x * v.x + v.y * v.y + v.z * v.z + v.w * v.w;
#pragma unroll
  for (int off = 32; off; off >>= 1) ss += __shfl_xor(ss, off, 64);
  __shared__ float red[4];
  if ((t & 63) == 0) red[t >> 6] = ss;
  __syncthreads();
  ss = red[0] + red[1] + red[2] + red[3];
  const float rs = rsqrtf(ss * (1.0f / 1024.0f) + 1e-6f);
  const float4 gv = ((const float4*)g)[t];
  __hip_bfloat16* o = out + (size_t)row * 1024 + t * 4;
  o[0] = __float2bfloat16(v.x * rs * gv.x);
  o[1] = __float2bfloat16(v.y * rs * gv.y);
  o[2] = __float2bfloat16(v.z * rs * gv.z);
  o[3] = __float2bfloat16(v.w * rs * gv.w);
  if (dinit) {
    const float4 bv = ((const float4*)bias)[t];
    float4 d;
    d.x = v.x + bv.x; d.y = v.y + bv.y; d.z = v.z + bv.z; d.w = v.w + bv.w;
    ((float4*)(dinit + (size_t)row * 1024))[t] = d;
  }
}

// ---------------- legacy GEMM (Wo, FFN2): C = A @ BT^T (+epilogue) ---------
// MODE 1: outf = resid + C   MODE 4: atomicAdd(outf, C)
template <int MODE, int MT, int PX, int PY>
__global__ __launch_bounds__(256, 2) void gemm_bt(
    const __hip_bfloat16* __restrict__ A,
    const __hip_bfloat16* __restrict__ BT,
    const float* __restrict__ bias,
    const float* __restrict__ resid,
    __hip_bfloat16* __restrict__ outb,
    float* __restrict__ outf,
    int M, int N, int K, int Ksub)
{
  __shared__ __align__(16) __hip_bfloat16 As[32 * MT * 64];
  __shared__ __align__(16) __hip_bfloat16 Bs[128 * 64];
  const int tid = threadIdx.x;
  const int wave = tid >> 6, lane = tid & 63;
  const int quad = lane >> 4, l16 = lane & 15;

  int bx = blockIdx.x, by = blockIdx.y;
  {
    const int id = by * gridDim.x + bx;
    const int k = id & 7, s = id >> 3;
    const int pw = gridDim.x / PX, ph = gridDim.y / PY;
    bx = (k % PX) * pw + (s % pw);
    by = (k / PX) * ph + (s / pw);
  }
  const int m0 = by * (32 * MT), n0 = bx * 128;
  const size_t kb = (size_t)blockIdx.z * Ksub;
  const int wr = (wave >> 1) * (16 * MT), wc = (wave & 1) * 64;
  const int lrow = lane >> 3;
  const int scol = ((lane & 7) ^ lrow) * 8;

  v4f acc[MT][4];
#pragma unroll
  for (int i = 0; i < MT; i++)
#pragma unroll
    for (int j = 0; j < 4; j++)
#pragma unroll
      for (int c = 0; c < 4; c++) acc[i][j][c] = 0.0f;

  for (int k0 = 0; k0 < Ksub; k0 += 64) {
#pragma unroll
    for (int i = 0; i < MT + 4; i++) {
      const int c = wave * (MT + 4) + i;
      if (c < 4 * MT) {
        async_ld16(A + (size_t)(m0 + c * 8 + lrow) * K + kb + k0 + scol, As + c * 512);
      } else {
        const int cb = c - 4 * MT;
        async_ld16(BT + (size_t)(n0 + cb * 8 + lrow) * K + kb + k0 + scol,
                   Bs + cb * 512);
      }
    }
    __syncthreads();
#pragma unroll
    for (int ks = 0; ks < 64; ks += 32) {
      v8bf af[MT], bfr[4];
#pragma unroll
      for (int mt = 0; mt < MT; mt++)
        af[mt] = FRAG(As, wr + mt * 16 + l16, ks + quad * 8);
#pragma unroll
      for (int nt = 0; nt < 4; nt++)
        bfr[nt] = FRAG(Bs, wc + nt * 16 + l16, ks + quad * 8);
#pragma unroll
      for (int mt = 0; mt < MT; mt++)
#pragma unroll
        for (int nt = 0; nt < 4; nt++)
          acc[mt][nt] = __builtin_amdgcn_mfma_f32_16x16x32_bf16(
              af[mt], bfr[nt], acc[mt][nt], 0, 0, 0);
    }
    __syncthreads();
  }

#pragma unroll
  for (int mt = 0; mt < MT; mt++) {
#pragma unroll
    for (int r = 0; r < 4; r++) {
      const int gm = m0 + wr + mt * 16 + quad * 4 + r;
#pragma unroll
      for (int nt = 0; nt < 4; nt++) {
        const int gn = n0 + wc + nt * 16 + l16;
        float v = acc[mt][nt][r];
        if (MODE == 0) {
          outb[(size_t)gm * N + gn] = __float2bfloat16(v);
        } else if (MODE == 1) {
          outf[(size_t)gm * N + gn] = resid[(size_t)gm * N + gn] + v;
        } else if (MODE == 2) {
          v += bias[gn];
          const float u = 0.7978845608f * (v + 0.044715f * v * v * v);
          const float e = EXP2F(u * 2.885390082f);
          const float th = 1.0f - 2.0f * __builtin_amdgcn_rcpf(e + 1.0f);
          v = 0.5f * v * (1.0f + th);
          outb[(size_t)gm * N + gn] = __float2bfloat16(v);
        } else {
          atomicAdd(&outf[(size_t)gm * N + gn], v);
        }
      }
    }
  }
}

// ---------------- GEMM 256x256 8-phase (counted-vmcnt schedule) ------------
// C = A @ BT^T. A [M][K] bf16, BT [N][K] bf16. BM=BN=256, BK=64, 512 thr.
// 8 waves (2M x 4N); per-wave 128x64 output as STRIDED halves:
//   rows: mh*128 + wm*64 + (0..63)   cols: nh*128 + wn*32 + (0..31)
// Per K-tile, 4 phases, quadrant order (0,0),(0,1),(1,1),(1,0); each phase:
//   { FRAG ds_reads | issue 1 half-tile stage | s_barrier |
//     setprio(1) 16xMFMA setprio(0) | [P3: s_waitcnt vmcnt(4)] | s_barrier }
// m201 configuration: compiler-visible ds_reads (backend inserts fine-grained
// lgkmcnt), bare s_barrier, inline asm ONLY for counted vmcnt. No clobbers,
// no sched_barriers (R9/R10 post-mortems: both defeat the pipeline).
// Stage ledger (steady state), half-stages of tile t+1/t+2 (2 loads/wave):
//   P0(t): A1(t+1)  P1(t): B0(t+1)  P2(t): A0(t+2)  P3(t): B1(t+2)
//   wait@P3(t): 12 outstanding -> vmcnt(4) drains 8 oldest = ALL of t+1,
//   leaves t+2's {A0,B1}. Tail degrades vmcnt(4)->vmcnt(0)->none.
// Write-after-read safety: each staged region's last LDS read is >=2
// barriers before the stage lands (A0@P0, B0@P0, B1@P1, A1@P2).
// MODE 0: outb=bf16(C)   MODE 2: outb=bf16(gelu(C+bias))
template <int MODE, int PX, int PY>
__global__ __launch_bounds__(512, 2) void gemm256(
    const __hip_bfloat16* __restrict__ A,
    const __hip_bfloat16* __restrict__ BT,
    const float* __restrict__ bias,
    __hip_bfloat16* __restrict__ outb,
    float* __restrict__ outf,
    int M, int N, int K, int Ksub)
{
  __shared__ __align__(16) __hip_bfloat16 As[2 * 256 * 64];  // 64 KiB
  __shared__ __align__(16) __hip_bfloat16 Bs[2 * 256 * 64];  // 64 KiB
  (void)M; (void)outf;
  const int tid = threadIdx.x;
  const int wave = tid >> 6, lane = tid & 63;
  const int quad = lane >> 4, l16 = lane & 15;
  const int wm = wave >> 2, wn = wave & 3;
  const int lrow = lane >> 3, scol = ((lane & 7) ^ lrow) * 8;

  int bx = blockIdx.x, by = blockIdx.y;
  {
    const int id = by * gridDim.x + bx;
    const int k = id & 7, s = id >> 3;
    const int pw = gridDim.x / PX, ph = gridDim.y / PY;
    bx = (k % PX) * pw + (s % pw);
    by = (k / PX) * ph + (s / pw);
  }
  const int m0 = by * 256, n0 = bx * 256;
  const size_t kb = (size_t)blockIdx.z * Ksub;
  const int NT = Ksub >> 6;
  const int cg = wave * 2;  // this wave's 2 row-group slots (of 16 per half)

  auto stageA = [&](int h, int tt) {
#pragma unroll
    for (int j = 0; j < 2; j++) {
      const int rg = cg + j;
      async_ld16(A + (size_t)(m0 + h * 128 + rg * 8 + lrow) * K + kb + tt * 64 + scol,
                 As + ((tt & 1) * 16384 + (h * 128 + rg * 8) * 64));
    }
  };
  auto stageB = [&](int h, int tt) {
#pragma unroll
    for (int j = 0; j < 2; j++) {
      const int rg = cg + j;
      async_ld16(BT + (size_t)(n0 + h * 128 + rg * 8 + lrow) * K + kb + tt * 64 + scol,
                 Bs + ((tt & 1) * 16384 + (h * 128 + rg * 8) * 64));
    }
  };

  v4f acc[8][4];
#pragma unroll
  for (int i = 0; i < 8; i++)
#pragma unroll
    for (int j = 0; j < 4; j++)
#pragma unroll
      for (int c = 0; c < 4; c++) acc[i][j][c] = 0.0f;

  // prologue: tile0 {A0,B0,B1,A1} + tile1 {A0,B1}; drain tile0 (8 of 12)
  stageA(0, 0); stageB(0, 0); stageB(1, 0); stageA(1, 0);
  if (NT > 1) {
    stageA(0, 1); stageB(1, 1);
    asm volatile("s_waitcnt vmcnt(4)");
  } else {
    asm volatile("s_waitcnt vmcnt(0)");
  }
  __builtin_amdgcn_s_barrier();

#define RA(mh)                                                              \
  _Pragma("unroll") for (int mt = 0; mt < 4; mt++)                          \
      _Pragma("unroll") for (int ks = 0; ks < 2; ks++)                      \
          af[mt][ks] =                                                      \
              FRAG(Ab, (mh) * 128 + wm * 64 + mt * 16 + l16, ks * 32 + quad * 8)
#define RB(dst, nh)                                                         \
  _Pragma("unroll") for (int nt = 0; nt < 2; nt++)                          \
      _Pragma("unroll") for (int ks = 0; ks < 2; ks++)                      \
          dst[nt][ks] =                                                     \
              FRAG(Bb, (nh) * 128 + wn * 32 + nt * 16 + l16, ks * 32 + quad * 8)
#define MM16(mh, bsrc, nh)                                                  \
  __builtin_amdgcn_s_setprio(1);                                            \
  _Pragma("unroll") for (int mt = 0; mt < 4; mt++)                          \
      _Pragma("unroll") for (int nt = 0; nt < 2; nt++)                      \
          _Pragma("unroll") for (int ks = 0; ks < 2; ks++)                  \
              acc[(mh) * 4 + mt][(nh) * 2 + nt] =                           \
                  __builtin_amdgcn_mfma_f32_16x16x32_bf16(                  \
                      af[mt][ks], bsrc[nt][ks],                             \
                      acc[(mh) * 4 + mt][(nh) * 2 + nt], 0, 0, 0);          \
  __builtin_amdgcn_s_setprio(0)

  for (int t = 0; t < NT; ++t) {
    const __hip_bfloat16* Ab = As + (t & 1) * 16384;
    const __hip_bfloat16* Bb = Bs + (t & 1) * 16384;
    v8bf af[4][2], b0[2][2], b1[2][2];
    // ---- P0: quadrant (0,0)
    RA(0); RB(b0, 0);
    if (t + 1 < NT) stageA(1, t + 1);
    __builtin_amdgcn_s_barrier();
    MM16(0, b0, 0);
    __builtin_amdgcn_s_barrier();
    // ---- P1: quadrant (0,1)
    RB(b1, 1);
    if (t + 1 < NT) stageB(0, t + 1);
    __builtin_amdgcn_s_barrier();
    MM16(0, b1, 1);
    __builtin_amdgcn_s_barrier();
    // ---- P2: quadrant (1,1)
    RA(1);
    if (t + 2 < NT) stageA(0, t + 2);
    __builtin_amdgcn_s_barrier();
    MM16(1, b1, 1);
    __builtin_amdgcn_s_barrier();
    // ---- P3: quadrant (1,0) — no new LDS reads (af(1), b0 already in regs)
    if (t + 2 < NT) stageB(1, t + 2);
    MM16(1, b0, 0);
    if (t + 2 < NT) {
      asm volatile("s_waitcnt vmcnt(4)");  // drain ALL of tile t+1
    } else if (t + 1 < NT) {
      asm volatile("s_waitcnt vmcnt(0)");  // tail drain
    }
    __builtin_amdgcn_s_barrier();
  }
#undef RA
#undef RB
#undef MM16

  // epilogue: C/D layout col=lane&15, row=quad*4+reg
#pragma unroll
  for (int ni = 0; ni < 4; ni++) {
    const int gn = n0 + (ni >> 1) * 128 + wn * 32 + (ni & 1) * 16 + l16;
    float bcol = 0.0f;
    if (MODE == 2) bcol = bias[gn];
#pragma unroll
    for (int mi = 0; mi < 8; mi++) {
      const int gmb = m0 + (mi >> 2) * 128 + wm * 64 + (mi & 3) * 16 + quad * 4;
#pragma unroll
      for (int r = 0; r < 4; r++) {
        float v = acc[mi][ni][r];
        const size_t idx = (size_t)(gmb + r) * N + gn;
        if (MODE == 0) {
          outb[idx] = __float2bfloat16(v);
        } else {
          v += bcol;
          // tanh-GELU (max |err| ~1e-3 in h -> <1e-3 in final output)
          const float u = 0.7978845608f * (v + 0.044715f * v * v * v);
          const float e = EXP2F(u * 2.885390082f);  // exp(2u)
          const float th = 1.0f - 2.0f * __builtin_amdgcn_rcpf(e + 1.0f);
          v = 0.5f * v * (1.0f + th);
          outb[idx] = __float2bfloat16(v);
        }
      }
    }
  }
}

// ---------------- flash attention (causal, no-max exp2 softmax) ------------
__global__ __launch_bounds__(256, 2) void attn_kernel(
    const __hip_bfloat16* __restrict__ QKV,
    const __hip_bfloat16* __restrict__ VTg,
    __hip_bfloat16* __restrict__ Y)
{
  __shared__ __align__(16) __hip_bfloat16 Ks[2 * 64 * 64];
  __shared__ __align__(16) __hip_bfloat16 Vs[2 * 64 * 64];
  __shared__ __align__(16) __hip_bfloat16 PsA[64 * 64];
  __shared__ __align__(16) __hip_bfloat16 PsB[64 * 64];

  const int tid = threadIdx.x;
  const int wave = tid >> 6, lane = tid & 63;
  const int quad = lane >> 4, l16 = lane & 15;
  const int blk = blockIdx.x;
  const int p = blk & 15, h = (blk >> 4) & 15, b = blk >> 8;
  const int qa = p, qb = 31 - p, kmax = qb;
  const size_t rowbase = (size_t)b * T_SEQ;
  const size_t vbase = (size_t)(b * 16 + h) * 64;
  const int lrow = lane >> 3, scol = ((lane & 7) ^ (lane >> 3)) * 8;

  const float QSC = 0.125f * 1.44269504f;
  v8bf aqA[2], aqB[2];
#pragma unroll
  for (int ks = 0; ks < 2; ks++) {
    v8bf q = *(const v8bf*)(QKV + (rowbase + qa * 64 + wave * 16 + l16) * 3072 +
                            h * 64 + ks * 32 + quad * 8);
#pragma unroll
    for (int j = 0; j < 8; j++) aqA[ks][j] = (__bf16)((float)q[j] * QSC);
    q = *(const v8bf*)(QKV + (rowbase + qb * 64 + wave * 16 + l16) * 3072 +
                       h * 64 + ks * 32 + quad * 8);
#pragma unroll
    for (int j = 0; j < 8; j++) aqB[ks][j] = (__bf16)((float)q[j] * QSC);
  }

  v4f oA[4], oB[4];
  float lpA[4], lpB[4];
#pragma unroll
  for (int i = 0; i < 4; i++) {
    lpA[i] = 0.0f; lpB[i] = 0.0f;
#pragma unroll
    for (int c = 0; c < 4; c++) { oA[i][c] = 0.0f; oB[i][c] = 0.0f; }
  }

  auto stage = [&](int kt, int buf) {
#pragma unroll
    for (int i = 0; i < 2; i++) {
      const int r8 = i * 32 + wave * 8;
      const int rr = r8 + lrow;
      async_ld16(QKV + (rowbase + kt * 64 + rr) * 3072 + 1024 + h * 64 + scol,
                 Ks + buf * 4096 + r8 * 64);
      async_ld16(VTg + (vbase + rr) * T_SEQ + kt * 64 + scol,
                 Vs + buf * 4096 + r8 * 64);
    }
  };
  stage(0, 0);

  auto softmax_store = [&](v4f s[4], float lp[4], __hip_bfloat16* Ps, bool diag) {
    if (diag) {
#pragma unroll
      for (int nt = 0; nt < 4; nt++) {
        const int colr = nt * 16 + l16;
#pragma unroll
        for (int r = 0; r < 4; r++)
          if (colr > wave * 16 + quad * 4 + r) s[nt][r] = -30000.0f;
      }
    }
#pragma unroll
    for (int r = 0; r < 4; r++) {
      const int row = wave * 16 + quad * 4 + r;
      const int rsw = (quad * 4 + r) & 7;
#pragma unroll
      for (int nt = 0; nt < 4; nt++) {
        const float e = EXP2F(s[nt][r]);
        lp[r] += e;
        const int chunk = (nt * 2 + (l16 >> 3)) ^ rsw;
        Ps[row * 64 + (chunk << 3) + (l16 & 7)] = __float2bfloat16(e);
      }
    }
  };

  for (int kt = 0; kt <= kmax; kt++) {
    __syncthreads();
    if (kt < kmax) stage(kt + 1, (kt + 1) & 1);
    const __hip_bfloat16* Kb = Ks + (kt & 1) * 4096;
    const __hip_bfloat16* Vb = Vs + (kt & 1) * 4096;
    const bool doA = (kt <= qa);

    {
      v8bf kf[2][4];
#pragma unroll
      for (int ks = 0; ks < 2; ks++)
#pragma unroll
        for (int nt = 0; nt < 4; nt++)
          kf[ks][nt] = FRAG(Kb, nt * 16 + l16, ks * 32 + quad * 8);

      v4f sB[4];
#pragma unroll
      for (int nt = 0; nt < 4; nt++)
#pragma unroll
        for (int c = 0; c < 4; c++) sB[nt][c] = 0.0f;
#pragma unroll
      for (int ks = 0; ks < 2; ks++)
#pragma unroll
        for (int nt = 0; nt < 4; nt++)
          sB[nt] = __builtin_amdgcn_mfma_f32_16x16x32_bf16(aqB[ks], kf[ks][nt],
                                                           sB[nt], 0, 0, 0);
      softmax_store(sB, lpB, PsB, kt == qb);

      if (doA) {
        v4f sA[4];
#pragma unroll
        for (int nt = 0; nt < 4; nt++)
#pragma unroll
          for (int c = 0; c < 4; c++) sA[nt][c] = 0.0f;
#pragma unroll
        for (int ks = 0; ks < 2; ks++)
#pragma unroll
          for (int nt = 0; nt < 4; nt++)
            sA[nt] = __builtin_amdgcn_mfma_f32_16x16x32_bf16(aqA[ks], kf[ks][nt],
                                                             sA[nt], 0, 0, 0);
        softmax_store(sA, lpA, PsA, kt == qa);
      }
    }

    {
      v8bf vf[2][4];
#pragma unroll
      for (int ks = 0; ks < 2; ks++)
#pragma unroll
        for (int nt = 0; nt < 4; nt++)
          vf[ks][nt] = FRAG(Vb, nt * 16 + l16, ks * 32 + quad * 8);
#pragma unroll
      for (int ks = 0; ks < 2; ks++) {
        const v8bf apB = FRAG(PsB, wave * 16 + l16, ks * 32 + quad * 8);
#pragma unroll
        for (int nt = 0; nt < 4; nt++)
          oB[nt] = __builtin_amdgcn_mfma_f32_16x16x32_bf16(apB, vf[ks][nt],
                                                           oB[nt], 0, 0, 0);
      }
      if (doA) {
#pragma unroll
        for (int ks = 0; ks < 2; ks++) {
          const v8bf apA = FRAG(PsA, wave * 16 + l16, ks * 32 + quad * 8);
#pragma unroll
          for (int nt = 0; nt < 4; nt++)
            oA[nt] = __builtin_amdgcn_mfma_f32_16x16x32_bf16(apA, vf[ks][nt],
                                                             oA[nt], 0, 0, 0);
        }
      }
    }
  }

#pragma unroll
  for (int r = 0; r < 4; r++) {
    float la = lpA[r], lb = lpB[r];
#pragma unroll
    for (int off = 1; off < 16; off <<= 1) {
      la += __shfl_xor(la, off, 16);
      lb += __shfl_xor(lb, off, 16);
    }
    const float ila = 1.0f / la, ilb = 1.0f / lb;
#pragma unroll
    for (int nt = 0; nt < 4; nt++) {
      Y[(rowbase + qa * 64 + wave * 16 + quad * 4 + r) * 1024 + h * 64 + nt * 16 + l16] =
          __float2bfloat16(oA[nt][r] * ila);
      Y[(rowbase + qb * 64 + wave * 16 + quad * 4 + r) * 1024 + h * 64 + nt * 16 + l16] =
          __float2bfloat16(oB[nt][r] * ilb);
    }
  }
}

// ---------------------------------------------------------------------------
extern "C" void kernel_launch(void* const* d_in, const int* in_sizes, int n_in,
                              void* d_out, int out_size, void* d_ws, size_t ws_size,
                              hipStream_t stream)
{
  const float* x  = (const float*)d_in[0];
  const float* Wq = (const float*)d_in[1];
  const float* Wk = (const float*)d_in[2];
  const float* Wv = (const float*)d_in[3];
  const float* Wo = (const float*)d_in[4];
  const float* W1 = (const float*)d_in[5];
  const float* b1 = (const float*)d_in[6];
  const float* W2 = (const float*)d_in[7];
  const float* b2 = (const float*)d_in[8];
  const float* g1 = (const float*)d_in[9];
  const float* g2 = (const float*)d_in[10];

  uint8_t* ws = (uint8_t*)d_ws;
  __hip_bfloat16* WqkvT = (__hip_bfloat16*)(ws + 0);
  __hip_bfloat16* WoT   = (__hip_bfloat16*)(ws + 6291456);
  __hip_bfloat16* W1T   = (__hip_bfloat16*)(ws + 8388608);
  __hip_bfloat16* W2T   = (__hip_bfloat16*)(ws + 16777216);
  float*          x1    = (float*)(ws + 25165824);
  __hip_bfloat16* xn    = (__hip_bfloat16*)(ws + 41943040);
  __hip_bfloat16* Ybuf  = (__hip_bfloat16*)(ws + 41943040);
  __hip_bfloat16* QKV   = (__hip_bfloat16*)(ws + 50331648);
  __hip_bfloat16* VTg   = (__hip_bfloat16*)(ws + 75497472);
  __hip_bfloat16* Hbuf  = (__hip_bfloat16*)(ws + 50331648);

  const dim3 tb(32, 8);
  transpose_w4<<<dim3(32, 32, 4), tb, 0, stream>>>(Wq, Wk, Wv, Wo, WqkvT);
  transpose_w<<<dim3(128, 32), tb, 0, stream>>>(W1, W1T, 1024, 4096, 1024);
  transpose_w<<<dim3(32, 128), tb, 0, stream>>>(W2, W2T, 4096, 1024, 4096);

  rmsnorm_kernel<<<4096, 256, 0, stream>>>(x, g1, xn, nullptr, nullptr);
  // QKV: 256^2 8-phase, grid (12,16) = 192 blocks; XCD patches 3x8
  gemm256<0, 4, 2><<<dim3(12, 16), 512, 0, stream>>>(
      xn, WqkvT, nullptr, QKV, nullptr, 4096, 3072, 1024, 1024);
  transpose_v<<<dim3(64, 64), tb, 0, stream>>>(QKV, VTg);
  attn_kernel<<<512, 256, 0, stream>>>(QKV, VTg, Ybuf);
  // Wo: legacy structure (small N; 256^2 grid would be 64 blocks)
  gemm_bt<1, 2, 1, 8><<<dim3(8, 64), 256, 0, stream>>>(
      Ybuf, WoT, nullptr, x, nullptr, x1, 4096, 1024, 1024, 1024);
  // rmsnorm2 also pre-initializes d_out = x1 + b2 (split-K atomic target)
  rmsnorm_kernel<<<4096, 256, 0, stream>>>(x1, g2, xn, b2, (float*)d_out);
  // FFN1: 256^2 8-phase, grid (16,16) = 256 blocks (1/CU); XCD patches 4x8
  gemm256<2, 4, 2><<<dim3(16, 16), 512, 0, stream>>>(
      xn, W1T, b1, Hbuf, nullptr, 4096, 4096, 1024, 1024);
  // FFN2: legacy split-K=2, MT=2 (R6/R8 best): 1024 blocks (4/CU);
  // partials atomicAdd into pre-initialized d_out
  gemm_bt<4, 2, 1, 8><<<dim3(8, 64, 2), 256, 0, stream>>>(
      Hbuf, W2T, nullptr, nullptr, nullptr, (float*)d_out, 4096, 1024, 4096, 2048);
}

// Round 5
// 323.192 us; speedup vs baseline: 1.0921x; 1.0038x over previous
//
#include <hip/hip_runtime.h>
#include <hip/hip_bf16.h>
#include <math.h>
#include <stdint.h>

// ---------------------------------------------------------------------------
// Transformer block: x + attn(rms(x,g1)) -> x1 ; x1 + ffn(rms(x1,g2))
// B=2 T=2048 D=1024 H=16 Dh=64 FF=4096. All GEMMs bf16 MFMA 16x16x32.
// R13 == R12 resubmitted (R4 bench was an infra failure: container acquire
//  failed twice; kernel never ran).
// R12: abandon counted-vmcnt-across-barriers (R9/R10/R11 all ran at legacy
//  speed; ROCm's waitcnt pass drains vmcnt before ds_reads that may alias
//  outstanding LDS-DMA, degenerating every variant to drain-per-phase).
//  gemm256 is now the PLAIN-HIP 2-phase dbuf (m230-V0/m248: 655-682 TF
//  refcheck'd at K=1024): 256x256 tile, BK=64, 8 waves, stage-next-tile
//  FIRST, then 24 ds_reads + 64 MFMA/wave, then ONE __syncthreads per
//  K-tile (its implicit vmcnt(0) drain sits a full compute phase after the
//  stage issue). No inline asm at all. attn: + setprio(1) around MFMA
//  clusters (T5, +4-7% measured on attn).
// LDS tiles use XOR-swizzled 16B chunks (chunk j of row r lives at j^(r&7));
// rocprof shows SQ_LDS_BANK_CONFLICT == 0 for this scheme.
// ---------------------------------------------------------------------------

typedef __bf16 v8bf  __attribute__((ext_vector_type(8)));
typedef float  v4f   __attribute__((ext_vector_type(4)));

#define T_SEQ 2048
#define EXP2F(x) __builtin_amdgcn_exp2f(x)  // v_exp_f32 (2^x)

// swizzled fragment read: row R, k-elem offset ko (multiple of 8)
#define FRAG(base, R, ko) \
  (*(const v8bf*)((base) + (R) * 64 + (((((ko) >> 3) ^ ((R) & 7))) << 3)))

__device__ __forceinline__ void async_ld16(const void* g, void* l) {
  // global -> LDS direct, 16B/lane. LDS dest is wave-uniform base + lane*16.
  __builtin_amdgcn_global_load_lds(
      (const __attribute__((address_space(1))) uint32_t*)g,
      (__attribute__((address_space(3))) uint32_t*)l, 16, 0, 0);
}

// ---------------- 4x weight transpose (Wq,Wk,Wv,Wo) fused ------------------
__global__ __launch_bounds__(256) void transpose_w4(
    const float* __restrict__ Wq, const float* __restrict__ Wk,
    const float* __restrict__ Wv, const float* __restrict__ Wo,
    __hip_bfloat16* __restrict__ out)
{
  __shared__ float tile[32][33];
  const int z = blockIdx.z;
  const float* W = z == 0 ? Wq : z == 1 ? Wk : z == 2 ? Wv : Wo;
  const int n0 = blockIdx.x * 32, k0 = blockIdx.y * 32;
  const int tx = threadIdx.x, ty = threadIdx.y;  // 32 x 8
#pragma unroll
  for (int i = 0; i < 32; i += 8)
    tile[ty + i][tx] = W[(size_t)(k0 + ty + i) * 1024 + n0 + tx];
  __syncthreads();
  __hip_bfloat16* o = out + (size_t)z * 1024 * 1024;
#pragma unroll
  for (int i = 0; i < 32; i += 8)
    o[(size_t)(n0 + ty + i) * 1024 + k0 + tx] = __float2bfloat16(tile[tx][ty + i]);
}

// ---------------- generic weight transpose ----------------------------------
__global__ __launch_bounds__(256) void transpose_w(
    const float* __restrict__ W, __hip_bfloat16* __restrict__ WT,
    int K, int N, int ldo)
{
  __shared__ float tile[32][33];
  const int n0 = blockIdx.x * 32, k0 = blockIdx.y * 32;
  const int tx = threadIdx.x, ty = threadIdx.y;  // 32 x 8
#pragma unroll
  for (int i = 0; i < 32; i += 8)
    tile[ty + i][tx] = W[(size_t)(k0 + ty + i) * N + n0 + tx];
  __syncthreads();
#pragma unroll
  for (int i = 0; i < 32; i += 8)
    WT[(size_t)(n0 + ty + i) * ldo + k0 + tx] = __float2bfloat16(tile[tx][ty + i]);
}

// ---------------- V transpose: QKV V-part -> VTg[b][h][d][t] ---------------
__global__ __launch_bounds__(256) void transpose_v(
    const __hip_bfloat16* __restrict__ QKV, __hip_bfloat16* __restrict__ VTg)
{
  __shared__ float tile[32][33];
  const int t0 = blockIdx.x * 32;
  const int bh = blockIdx.y >> 1;
  const int dt = (blockIdx.y & 1) * 32;
  const int b = bh >> 4, h = bh & 15;
  const int tx = threadIdx.x, ty = threadIdx.y;  // 32 x 8
#pragma unroll
  for (int i = 0; i < 32; i += 8)
    tile[ty + i][tx] = __bfloat162float(
        QKV[(size_t)(b * T_SEQ + t0 + ty + i) * 3072 + 2048 + h * 64 + dt + tx]);
  __syncthreads();
#pragma unroll
  for (int i = 0; i < 32; i += 8)
    VTg[((size_t)bh * 64 + dt + ty + i) * T_SEQ + t0 + tx] =
        __float2bfloat16(tile[tx][ty + i]);
}

// ---------------- RMSNorm (fp32 in -> bf16 out, optional d_out init) -------
__global__ __launch_bounds__(256) void rmsnorm_kernel(
    const float* __restrict__ x, const float* __restrict__ g,
    __hip_bfloat16* __restrict__ out,
    const float* __restrict__ bias, float* __restrict__ dinit)
{
  const int row = blockIdx.x;
  const int t = threadIdx.x;
  const float4 v = ((const float4*)(x + (size_t)row * 1024))[t];
  float ss = v.x * v.x + v.y * v.y + v.z * v.z + v.w * v.w;
#pragma unroll
  for (int off = 32; off; off >>= 1) ss += __shfl_xor(ss, off, 64);
  __shared__ float red[4];
  if ((t & 63) == 0) red[t >> 6] = ss;
  __syncthreads();
  ss = red[0] + red[1] + red[2] + red[3];
  const float rs = rsqrtf(ss * (1.0f / 1024.0f) + 1e-6f);
  const float4 gv = ((const float4*)g)[t];
  __hip_bfloat16* o = out + (size_t)row * 1024 + t * 4;
  o[0] = __float2bfloat16(v.x * rs * gv.x);
  o[1] = __float2bfloat16(v.y * rs * gv.y);
  o[2] = __float2bfloat16(v.z * rs * gv.z);
  o[3] = __float2bfloat16(v.w * rs * gv.w);
  if (dinit) {
    const float4 bv = ((const float4*)bias)[t];
    float4 d;
    d.x = v.x + bv.x; d.y = v.y + bv.y; d.z = v.z + bv.z; d.w = v.w + bv.w;
    ((float4*)(dinit + (size_t)row * 1024))[t] = d;
  }
}

// ---------------- legacy GEMM (Wo, FFN2): C = A @ BT^T (+epilogue) ---------
// MODE 1: outf = resid + C   MODE 4: atomicAdd(outf, C)
template <int MODE, int MT, int PX, int PY>
__global__ __launch_bounds__(256, 2) void gemm_bt(
    const __hip_bfloat16* __restrict__ A,
    const __hip_bfloat16* __restrict__ BT,
    const float* __restrict__ bias,
    const float* __restrict__ resid,
    __hip_bfloat16* __restrict__ outb,
    float* __restrict__ outf,
    int M, int N, int K, int Ksub)
{
  __shared__ __align__(16) __hip_bfloat16 As[32 * MT * 64];
  __shared__ __align__(16) __hip_bfloat16 Bs[128 * 64];
  const int tid = threadIdx.x;
  const int wave = tid >> 6, lane = tid & 63;
  const int quad = lane >> 4, l16 = lane & 15;

  int bx = blockIdx.x, by = blockIdx.y;
  {
    const int id = by * gridDim.x + bx;
    const int k = id & 7, s = id >> 3;
    const int pw = gridDim.x / PX, ph = gridDim.y / PY;
    bx = (k % PX) * pw + (s % pw);
    by = (k / PX) * ph + (s / pw);
  }
  const int m0 = by * (32 * MT), n0 = bx * 128;
  const size_t kb = (size_t)blockIdx.z * Ksub;
  const int wr = (wave >> 1) * (16 * MT), wc = (wave & 1) * 64;
  const int lrow = lane >> 3;
  const int scol = ((lane & 7) ^ lrow) * 8;

  v4f acc[MT][4];
#pragma unroll
  for (int i = 0; i < MT; i++)
#pragma unroll
    for (int j = 0; j < 4; j++)
#pragma unroll
      for (int c = 0; c < 4; c++) acc[i][j][c] = 0.0f;

  for (int k0 = 0; k0 < Ksub; k0 += 64) {
#pragma unroll
    for (int i = 0; i < MT + 4; i++) {
      const int c = wave * (MT + 4) + i;
      if (c < 4 * MT) {
        async_ld16(A + (size_t)(m0 + c * 8 + lrow) * K + kb + k0 + scol, As + c * 512);
      } else {
        const int cb = c - 4 * MT;
        async_ld16(BT + (size_t)(n0 + cb * 8 + lrow) * K + kb + k0 + scol,
                   Bs + cb * 512);
      }
    }
    __syncthreads();
#pragma unroll
    for (int ks = 0; ks < 64; ks += 32) {
      v8bf af[MT], bfr[4];
#pragma unroll
      for (int mt = 0; mt < MT; mt++)
        af[mt] = FRAG(As, wr + mt * 16 + l16, ks + quad * 8);
#pragma unroll
      for (int nt = 0; nt < 4; nt++)
        bfr[nt] = FRAG(Bs, wc + nt * 16 + l16, ks + quad * 8);
#pragma unroll
      for (int mt = 0; mt < MT; mt++)
#pragma unroll
        for (int nt = 0; nt < 4; nt++)
          acc[mt][nt] = __builtin_amdgcn_mfma_f32_16x16x32_bf16(
              af[mt], bfr[nt], acc[mt][nt], 0, 0, 0);
    }
    __syncthreads();
  }

#pragma unroll
  for (int mt = 0; mt < MT; mt++) {
#pragma unroll
    for (int r = 0; r < 4; r++) {
      const int gm = m0 + wr + mt * 16 + quad * 4 + r;
#pragma unroll
      for (int nt = 0; nt < 4; nt++) {
        const int gn = n0 + wc + nt * 16 + l16;
        float v = acc[mt][nt][r];
        if (MODE == 0) {
          outb[(size_t)gm * N + gn] = __float2bfloat16(v);
        } else if (MODE == 1) {
          outf[(size_t)gm * N + gn] = resid[(size_t)gm * N + gn] + v;
        } else if (MODE == 2) {
          v += bias[gn];
          const float u = 0.7978845608f * (v + 0.044715f * v * v * v);
          const float e = EXP2F(u * 2.885390082f);
          const float th = 1.0f - 2.0f * __builtin_amdgcn_rcpf(e + 1.0f);
          v = 0.5f * v * (1.0f + th);
          outb[(size_t)gm * N + gn] = __float2bfloat16(v);
        } else {
          atomicAdd(&outf[(size_t)gm * N + gn], v);
        }
      }
    }
  }
}

// ---------------- GEMM 256x256 2-phase dbuf (plain HIP) --------------------
// C = A @ BT^T. A [M][K] bf16, BT [N][K] bf16. BM=BN=256, BK=64, 512 thr.
// 8 waves (2M x 4N); per-wave 128x64 output as STRIDED halves:
//   rows: mh*128 + wm*64 + (0..63)   cols: nh*128 + wn*32 + (0..31)
// Per K-tile: { stage tile t+1 into buf^1 (8 x global_load_lds/thread) |
//   24 FRAG ds_reads + 64 MFMA per wave from buf | __syncthreads }.
// The sync's implicit vmcnt(0) drain sits one full compute phase after the
// stage issue -> prefetch latency hidden, 64 MFMA per drain (legacy: 32,
// drain immediately after issue). m230-V0/m248: 655-682 TF @ K=1024.
// Single barrier per K-tile is safe: all frag reads are consumed by MFMA
// (lgkm-waited) before the barrier; DMA targets the other buffer.
// MODE 0: outb=bf16(C)   MODE 2: outb=bf16(gelu(C+bias))
template <int MODE, int PX, int PY>
__global__ __launch_bounds__(512, 2) void gemm256(
    const __hip_bfloat16* __restrict__ A,
    const __hip_bfloat16* __restrict__ BT,
    const float* __restrict__ bias,
    __hip_bfloat16* __restrict__ outb,
    float* __restrict__ outf,
    int M, int N, int K, int Ksub)
{
  __shared__ __align__(16) __hip_bfloat16 As[2 * 256 * 64];  // 64 KiB
  __shared__ __align__(16) __hip_bfloat16 Bs[2 * 256 * 64];  // 64 KiB
  (void)M; (void)outf;
  const int tid = threadIdx.x;
  const int wave = tid >> 6, lane = tid & 63;
  const int quad = lane >> 4, l16 = lane & 15;
  const int wm = wave >> 2, wn = wave & 3;
  const int lrow = lane >> 3, scol = ((lane & 7) ^ lrow) * 8;

  int bx = blockIdx.x, by = blockIdx.y;
  {
    const int id = by * gridDim.x + bx;
    const int k = id & 7, s = id >> 3;
    const int pw = gridDim.x / PX, ph = gridDim.y / PY;
    bx = (k % PX) * pw + (s % pw);
    by = (k / PX) * ph + (s / pw);
  }
  const int m0 = by * 256, n0 = bx * 256;
  const size_t kb = (size_t)blockIdx.z * Ksub;
  const int NT = Ksub >> 6;
  const int cg = wave * 2;  // this wave's 2 row-group slots (of 16 per half)

  auto stageA = [&](int h, int tt) {
#pragma unroll
    for (int j = 0; j < 2; j++) {
      const int rg = cg + j;
      async_ld16(A + (size_t)(m0 + h * 128 + rg * 8 + lrow) * K + kb + tt * 64 + scol,
                 As + ((tt & 1) * 16384 + (h * 128 + rg * 8) * 64));
    }
  };
  auto stageB = [&](int h, int tt) {
#pragma unroll
    for (int j = 0; j < 2; j++) {
      const int rg = cg + j;
      async_ld16(BT + (size_t)(n0 + h * 128 + rg * 8 + lrow) * K + kb + tt * 64 + scol,
                 Bs + ((tt & 1) * 16384 + (h * 128 + rg * 8) * 64));
    }
  };

  v4f acc[8][4];
#pragma unroll
  for (int i = 0; i < 8; i++)
#pragma unroll
    for (int j = 0; j < 4; j++)
#pragma unroll
      for (int c = 0; c < 4; c++) acc[i][j][c] = 0.0f;

  // prologue: stage tile 0, drain (implicit in __syncthreads)
  stageA(0, 0); stageB(0, 0); stageA(1, 0); stageB(1, 0);
  __syncthreads();

  for (int t = 0; t < NT; ++t) {
    // stage NEXT tile first: its drain (sync below) is a full compute
    // phase away, so HBM/L2 latency hides under the 64 MFMA.
    if (t + 1 < NT) {
      stageA(0, t + 1); stageB(0, t + 1); stageA(1, t + 1); stageB(1, t + 1);
    }
    const __hip_bfloat16* Ab = As + (t & 1) * 16384;
    const __hip_bfloat16* Bb = Bs + (t & 1) * 16384;
#pragma unroll
    for (int ks = 0; ks < 2; ks++) {
      v8bf a[8], b[4];
#pragma unroll
      for (int mh = 0; mh < 2; mh++)
#pragma unroll
        for (int mt = 0; mt < 4; mt++)
          a[mh * 4 + mt] =
              FRAG(Ab, mh * 128 + wm * 64 + mt * 16 + l16, ks * 32 + quad * 8);
#pragma unroll
      for (int nh = 0; nh < 2; nh++)
#pragma unroll
        for (int nt = 0; nt < 2; nt++)
          b[nh * 2 + nt] =
              FRAG(Bb, nh * 128 + wn * 32 + nt * 16 + l16, ks * 32 + quad * 8);
#pragma unroll
      for (int mi = 0; mi < 8; mi++)
#pragma unroll
        for (int ni = 0; ni < 4; ni++)
          acc[mi][ni] = __builtin_amdgcn_mfma_f32_16x16x32_bf16(
              a[mi], b[ni], acc[mi][ni], 0, 0, 0);
    }
    if (t + 1 < NT) __syncthreads();
  }

  // epilogue: C/D layout col=lane&15, row=quad*4+reg
#pragma unroll
  for (int ni = 0; ni < 4; ni++) {
    const int gn = n0 + (ni >> 1) * 128 + wn * 32 + (ni & 1) * 16 + l16;
    float bcol = 0.0f;
    if (MODE == 2) bcol = bias[gn];
#pragma unroll
    for (int mi = 0; mi < 8; mi++) {
      const int gmb = m0 + (mi >> 2) * 128 + wm * 64 + (mi & 3) * 16 + quad * 4;
#pragma unroll
      for (int r = 0; r < 4; r++) {
        float v = acc[mi][ni][r];
        const size_t idx = (size_t)(gmb + r) * N + gn;
        if (MODE == 0) {
          outb[idx] = __float2bfloat16(v);
        } else {
          v += bcol;
          // tanh-GELU (max |err| ~1e-3 in h -> <1e-3 in final output)
          const float u = 0.7978845608f * (v + 0.044715f * v * v * v);
          const float e = EXP2F(u * 2.885390082f);  // exp(2u)
          const float th = 1.0f - 2.0f * __builtin_amdgcn_rcpf(e + 1.0f);
          v = 0.5f * v * (1.0f + th);
          outb[idx] = __float2bfloat16(v);
        }
      }
    }
  }
}

// ---------------- flash attention (causal, no-max exp2 softmax) ------------
__global__ __launch_bounds__(256, 2) void attn_kernel(
    const __hip_bfloat16* __restrict__ QKV,
    const __hip_bfloat16* __restrict__ VTg,
    __hip_bfloat16* __restrict__ Y)
{
  __shared__ __align__(16) __hip_bfloat16 Ks[2 * 64 * 64];
  __shared__ __align__(16) __hip_bfloat16 Vs[2 * 64 * 64];
  __shared__ __align__(16) __hip_bfloat16 PsA[64 * 64];
  __shared__ __align__(16) __hip_bfloat16 PsB[64 * 64];

  const int tid = threadIdx.x;
  const int wave = tid >> 6, lane = tid & 63;
  const int quad = lane >> 4, l16 = lane & 15;
  const int blk = blockIdx.x;
  const int p = blk & 15, h = (blk >> 4) & 15, b = blk >> 8;
  const int qa = p, qb = 31 - p, kmax = qb;
  const size_t rowbase = (size_t)b * T_SEQ;
  const size_t vbase = (size_t)(b * 16 + h) * 64;
  const int lrow = lane >> 3, scol = ((lane & 7) ^ (lane >> 3)) * 8;

  const float QSC = 0.125f * 1.44269504f;
  v8bf aqA[2], aqB[2];
#pragma unroll
  for (int ks = 0; ks < 2; ks++) {
    v8bf q = *(const v8bf*)(QKV + (rowbase + qa * 64 + wave * 16 + l16) * 3072 +
                            h * 64 + ks * 32 + quad * 8);
#pragma unroll
    for (int j = 0; j < 8; j++) aqA[ks][j] = (__bf16)((float)q[j] * QSC);
    q = *(const v8bf*)(QKV + (rowbase + qb * 64 + wave * 16 + l16) * 3072 +
                       h * 64 + ks * 32 + quad * 8);
#pragma unroll
    for (int j = 0; j < 8; j++) aqB[ks][j] = (__bf16)((float)q[j] * QSC);
  }

  v4f oA[4], oB[4];
  float lpA[4], lpB[4];
#pragma unroll
  for (int i = 0; i < 4; i++) {
    lpA[i] = 0.0f; lpB[i] = 0.0f;
#pragma unroll
    for (int c = 0; c < 4; c++) { oA[i][c] = 0.0f; oB[i][c] = 0.0f; }
  }

  auto stage = [&](int kt, int buf) {
#pragma unroll
    for (int i = 0; i < 2; i++) {
      const int r8 = i * 32 + wave * 8;
      const int rr = r8 + lrow;
      async_ld16(QKV + (rowbase + kt * 64 + rr) * 3072 + 1024 + h * 64 + scol,
                 Ks + buf * 4096 + r8 * 64);
      async_ld16(VTg + (vbase + rr) * T_SEQ + kt * 64 + scol,
                 Vs + buf * 4096 + r8 * 64);
    }
  };
  stage(0, 0);

  auto softmax_store = [&](v4f s[4], float lp[4], __hip_bfloat16* Ps, bool diag) {
    if (diag) {
#pragma unroll
      for (int nt = 0; nt < 4; nt++) {
        const int colr = nt * 16 + l16;
#pragma unroll
        for (int r = 0; r < 4; r++)
          if (colr > wave * 16 + quad * 4 + r) s[nt][r] = -30000.0f;
      }
    }
#pragma unroll
    for (int r = 0; r < 4; r++) {
      const int row = wave * 16 + quad * 4 + r;
      const int rsw = (quad * 4 + r) & 7;
#pragma unroll
      for (int nt = 0; nt < 4; nt++) {
        const float e = EXP2F(s[nt][r]);
        lp[r] += e;
        const int chunk = (nt * 2 + (l16 >> 3)) ^ rsw;
        Ps[row * 64 + (chunk << 3) + (l16 & 7)] = __float2bfloat16(e);
      }
    }
  };

  for (int kt = 0; kt <= kmax; kt++) {
    __syncthreads();
    if (kt < kmax) stage(kt + 1, (kt + 1) & 1);
    const __hip_bfloat16* Kb = Ks + (kt & 1) * 4096;
    const __hip_bfloat16* Vb = Vs + (kt & 1) * 4096;
    const bool doA = (kt <= qa);

    {
      v8bf kf[2][4];
#pragma unroll
      for (int ks = 0; ks < 2; ks++)
#pragma unroll
        for (int nt = 0; nt < 4; nt++)
          kf[ks][nt] = FRAG(Kb, nt * 16 + l16, ks * 32 + quad * 8);

      v4f sB[4];
#pragma unroll
      for (int nt = 0; nt < 4; nt++)
#pragma unroll
        for (int c = 0; c < 4; c++) sB[nt][c] = 0.0f;
      __builtin_amdgcn_s_setprio(1);
#pragma unroll
      for (int ks = 0; ks < 2; ks++)
#pragma unroll
        for (int nt = 0; nt < 4; nt++)
          sB[nt] = __builtin_amdgcn_mfma_f32_16x16x32_bf16(aqB[ks], kf[ks][nt],
                                                           sB[nt], 0, 0, 0);
      __builtin_amdgcn_s_setprio(0);
      softmax_store(sB, lpB, PsB, kt == qb);

      if (doA) {
        v4f sA[4];
#pragma unroll
        for (int nt = 0; nt < 4; nt++)
#pragma unroll
          for (int c = 0; c < 4; c++) sA[nt][c] = 0.0f;
        __builtin_amdgcn_s_setprio(1);
#pragma unroll
        for (int ks = 0; ks < 2; ks++)
#pragma unroll
          for (int nt = 0; nt < 4; nt++)
            sA[nt] = __builtin_amdgcn_mfma_f32_16x16x32_bf16(aqA[ks], kf[ks][nt],
                                                             sA[nt], 0, 0, 0);
        __builtin_amdgcn_s_setprio(0);
        softmax_store(sA, lpA, PsA, kt == qa);
      }
    }

    {
      v8bf vf[2][4];
#pragma unroll
      for (int ks = 0; ks < 2; ks++)
#pragma unroll
        for (int nt = 0; nt < 4; nt++)
          vf[ks][nt] = FRAG(Vb, nt * 16 + l16, ks * 32 + quad * 8);
      __builtin_amdgcn_s_setprio(1);
#pragma unroll
      for (int ks = 0; ks < 2; ks++) {
        const v8bf apB = FRAG(PsB, wave * 16 + l16, ks * 32 + quad * 8);
#pragma unroll
        for (int nt = 0; nt < 4; nt++)
          oB[nt] = __builtin_amdgcn_mfma_f32_16x16x32_bf16(apB, vf[ks][nt],
                                                           oB[nt], 0, 0, 0);
      }
      __builtin_amdgcn_s_setprio(0);
      if (doA) {
        __builtin_amdgcn_s_setprio(1);
#pragma unroll
        for (int ks = 0; ks < 2; ks++) {
          const v8bf apA = FRAG(PsA, wave * 16 + l16, ks * 32 + quad * 8);
#pragma unroll
          for (int nt = 0; nt < 4; nt++)
            oA[nt] = __builtin_amdgcn_mfma_f32_16x16x32_bf16(apA, vf[ks][nt],
                                                             oA[nt], 0, 0, 0);
        }
        __builtin_amdgcn_s_setprio(0);
      }
    }
  }

#pragma unroll
  for (int r = 0; r < 4; r++) {
    float la = lpA[r], lb = lpB[r];
#pragma unroll
    for (int off = 1; off < 16; off <<= 1) {
      la += __shfl_xor(la, off, 16);
      lb += __shfl_xor(lb, off, 16);
    }
    const float ila = 1.0f / la, ilb = 1.0f / lb;
#pragma unroll
    for (int nt = 0; nt < 4; nt++) {
      Y[(rowbase + qa * 64 + wave * 16 + quad * 4 + r) * 1024 + h * 64 + nt * 16 + l16] =
          __float2bfloat16(oA[nt][r] * ila);
      Y[(rowbase + qb * 64 + wave * 16 + quad * 4 + r) * 1024 + h * 64 + nt * 16 + l16] =
          __float2bfloat16(oB[nt][r] * ilb);
    }
  }
}

// ---------------------------------------------------------------------------
extern "C" void kernel_launch(void* const* d_in, const int* in_sizes, int n_in,
                              void* d_out, int out_size, void* d_ws, size_t ws_size,
                              hipStream_t stream)
{
  const float* x  = (const float*)d_in[0];
  const float* Wq = (const float*)d_in[1];
  const float* Wk = (const float*)d_in[2];
  const float* Wv = (const float*)d_in[3];
  const float* Wo = (const float*)d_in[4];
  const float* W1 = (const float*)d_in[5];
  const float* b1 = (const float*)d_in[6];
  const float* W2 = (const float*)d_in[7];
  const float* b2 = (const float*)d_in[8];
  const float* g1 = (const float*)d_in[9];
  const float* g2 = (const float*)d_in[10];

  uint8_t* ws = (uint8_t*)d_ws;
  __hip_bfloat16* WqkvT = (__hip_bfloat16*)(ws + 0);
  __hip_bfloat16* WoT   = (__hip_bfloat16*)(ws + 6291456);
  __hip_bfloat16* W1T   = (__hip_bfloat16*)(ws + 8388608);
  __hip_bfloat16* W2T   = (__hip_bfloat16*)(ws + 16777216);
  float*          x1    = (float*)(ws + 25165824);
  __hip_bfloat16* xn    = (__hip_bfloat16*)(ws + 41943040);
  __hip_bfloat16* Ybuf  = (__hip_bfloat16*)(ws + 41943040);
  __hip_bfloat16* QKV   = (__hip_bfloat16*)(ws + 50331648);
  __hip_bfloat16* VTg   = (__hip_bfloat16*)(ws + 75497472);
  __hip_bfloat16* Hbuf  = (__hip_bfloat16*)(ws + 50331648);

  const dim3 tb(32, 8);
  transpose_w4<<<dim3(32, 32, 4), tb, 0, stream>>>(Wq, Wk, Wv, Wo, WqkvT);
  transpose_w<<<dim3(128, 32), tb, 0, stream>>>(W1, W1T, 1024, 4096, 1024);
  transpose_w<<<dim3(32, 128), tb, 0, stream>>>(W2, W2T, 4096, 1024, 4096);

  rmsnorm_kernel<<<4096, 256, 0, stream>>>(x, g1, xn, nullptr, nullptr);
  // QKV: 256^2 2-phase, grid (12,16) = 192 blocks; XCD patches 3x8
  gemm256<0, 4, 2><<<dim3(12, 16), 512, 0, stream>>>(
      xn, WqkvT, nullptr, QKV, nullptr, 4096, 3072, 1024, 1024);
  transpose_v<<<dim3(64, 64), tb, 0, stream>>>(QKV, VTg);
  attn_kernel<<<512, 256, 0, stream>>>(QKV, VTg, Ybuf);
  // Wo: legacy structure (small N; 256^2 grid would be 64 blocks)
  gemm_bt<1, 2, 1, 8><<<dim3(8, 64), 256, 0, stream>>>(
      Ybuf, WoT, nullptr, x, nullptr, x1, 4096, 1024, 1024, 1024);
  // rmsnorm2 also pre-initializes d_out = x1 + b2 (split-K atomic target)
  rmsnorm_kernel<<<4096, 256, 0, stream>>>(x1, g2, xn, b2, (float*)d_out);
  // FFN1: 256^2 2-phase, grid (16,16) = 256 blocks (1/CU); XCD patches 4x8
  gemm256<2, 4, 2><<<dim3(16, 16), 512, 0, stream>>>(
      xn, W1T, b1, Hbuf, nullptr, 4096, 4096, 1024, 1024);
  // FFN2: legacy split-K=2, MT=2 (R6/R8 best): 1024 blocks (4/CU);
  // partials atomicAdd into pre-initialized d_out
  gemm_bt<4, 2, 1, 8><<<dim3(8, 64, 2), 256, 0, stream>>>(
      Hbuf, W2T, nullptr, nullptr, nullptr, (float*)d_out, 4096, 1024, 4096, 2048);
}